// Round 18
// baseline (4423.475 us; speedup 1.0000x reference)
//
#include <hip/hip_runtime.h>
#include <math.h>

#define S_LEN 32
#define B_N   16
#define H_N   1024
#define E_N   256
#define V_N   32000
#define KBEAM 4
#define DIN   1536
#define D2    2560   // DIN + H_N
#define R_N   64     // KBEAM * B_N rows of state
#define NDS   20     // K-slices for gates GEMM (128 each, 4 chunks)
#define NB    500    // stats/final col-blocks = V_N/64

typedef _Float16 f16;
typedef f16   f16x8 __attribute__((ext_vector_type(8)));
typedef float f32x4 __attribute__((ext_vector_type(4)));
#define MFMA(A,B,C) __builtin_amdgcn_mfma_f32_16x16x32_f16(A,B,C,0,0,0)

__device__ __forceinline__ float sigmf(float x){ return 1.0f/(1.0f+expf(-x)); }
__device__ __forceinline__ bool better(float v1,int i1,float v2,int i2){
  return (v1>v2) || (v1==v2 && i1<i2);
}
__device__ __forceinline__ void ins4(float bv,int bi,
    float&av0,float&av1,float&av2,float&av3,int&ai0,int&ai1,int&ai2,int&ai3){
  if (better(bv,bi,av3,ai3)){ av3=bv; ai3=bi;
    if (better(av3,ai3,av2,ai2)){ float t=av2;av2=av3;av3=t; int q=ai2;ai2=ai3;ai3=q;
      if (better(av2,ai2,av1,ai1)){ t=av1;av1=av2;av2=t; q=ai1;ai1=ai2;ai2=q;
        if (better(av1,ai1,av0,ai0)){ t=av0;av0=av1;av1=t; q=ai0;ai0=ai1;ai1=q; } } } }
}

// 4x4 FMA micro-tile into acc[4][4]
#define FMA16(w4, h4) { \
  acc[0][0]=fmaf(w4.x,h4.x,acc[0][0]); acc[0][1]=fmaf(w4.x,h4.y,acc[0][1]); \
  acc[0][2]=fmaf(w4.x,h4.z,acc[0][2]); acc[0][3]=fmaf(w4.x,h4.w,acc[0][3]); \
  acc[1][0]=fmaf(w4.y,h4.x,acc[1][0]); acc[1][1]=fmaf(w4.y,h4.y,acc[1][1]); \
  acc[1][2]=fmaf(w4.y,h4.z,acc[1][2]); acc[1][3]=fmaf(w4.y,h4.w,acc[1][3]); \
  acc[2][0]=fmaf(w4.z,h4.x,acc[2][0]); acc[2][1]=fmaf(w4.z,h4.y,acc[2][1]); \
  acc[2][2]=fmaf(w4.z,h4.z,acc[2][2]); acc[2][3]=fmaf(w4.z,h4.w,acc[2][3]); \
  acc[3][0]=fmaf(w4.w,h4.x,acc[3][0]); acc[3][1]=fmaf(w4.w,h4.y,acc[3][1]); \
  acc[3][2]=fmaf(w4.w,h4.z,acc[3][2]); acc[3][3]=fmaf(w4.w,h4.w,acc[3][3]); }

// ---- init
__global__ __launch_bounds__(256) void k_init(
    const float* __restrict__ enc_h_n, const float* __restrict__ enc_c_n,
    const float* __restrict__ enc_outputs, const float* __restrict__ enc_inputs,
    const float* __restrict__ embed, float* __restrict__ x, float* __restrict__ c){
  int r = blockIdx.x, tid = threadIdx.x, b = r & 15;
  float* xr = x + (size_t)r*D2;
  xr[tid]        = embed[E_N + tid];
  xr[E_N + tid]  = enc_inputs[b*E_N + tid];
  #pragma unroll
  for (int q=0;q<4;++q) xr[2*E_N + q*256 + tid] = enc_outputs[b*H_N + q*256 + tid];
  #pragma unroll
  for (int q=0;q<4;++q) xr[DIN + q*256 + tid]   = enc_h_n[b*H_N + q*256 + tid];
  #pragma unroll
  for (int q=0;q<4;++q) c[(size_t)r*H_N + q*256 + tid] = enc_c_n[b*H_N + q*256 + tid];
}

// ---- one-time: transpose + fp16-split w_out[1024][32000] -> whi/wlo [32000][1024]
// block 256 thr, tile 64 dd x 64 vocab; grid (500, 16).
__global__ __launch_bounds__(256) void k_convw(
    const float* __restrict__ w, f16* __restrict__ whi, f16* __restrict__ wlo){
  __shared__ f16 Th[64][66];
  __shared__ f16 Tl[64][66];
  int v0 = blockIdx.x*64, d0 = blockIdx.y*64;
  int tid = threadIdx.x;
  int r = tid >> 4, cq = (tid & 15)*4;
  #pragma unroll
  for (int rr=0; rr<4; ++rr){
    int d = r + rr*16;
    float4 x = *(const float4*)&w[(size_t)(d0+d)*V_N + v0 + cq];
    f16 h;
    h=(f16)x.x; Th[d][cq+0]=h; Tl[d][cq+0]=(f16)((x.x-(float)h)*4096.0f);
    h=(f16)x.y; Th[d][cq+1]=h; Tl[d][cq+1]=(f16)((x.y-(float)h)*4096.0f);
    h=(f16)x.z; Th[d][cq+2]=h; Tl[d][cq+2]=(f16)((x.z-(float)h)*4096.0f);
    h=(f16)x.w; Th[d][cq+3]=h; Tl[d][cq+3]=(f16)((x.w-(float)h)*4096.0f);
  }
  __syncthreads();
  int vr = tid >> 2, ds = (tid & 3)*16;
  f16x8 a, b2, c2, e2;
  #pragma unroll
  for (int i=0;i<8;++i){
    a[i]=Th[ds+i][vr];  b2[i]=Th[ds+8+i][vr];
    c2[i]=Tl[ds+i][vr]; e2[i]=Tl[ds+8+i][vr];
  }
  size_t ob = (size_t)(v0+vr)*1024 + d0 + ds;
  *(f16x8*)&whi[ob]   = a;  *(f16x8*)&whi[ob+8] = b2;
  *(f16x8*)&wlo[ob]   = c2; *(f16x8*)&wlo[ob+8] = e2;
}

// ---- gates GEMM: gpart[ks][64][4096]; grid (64, NDS), 256 thr.
#define GWLD(d, off) (*(const float4*)((((d) < DIN) ? (w_ih + (size_t)(d)*4096) \
                       : (w_hh + (size_t)((d)-DIN)*4096)) + (off)))
__global__ __launch_bounds__(256) void k_gates(
    const float* __restrict__ x, const float* __restrict__ w_ih,
    const float* __restrict__ w_hh, float* __restrict__ gpart){
  int tid = threadIdx.x;
  int jt = blockIdx.x, ks = blockIdx.y;
  int cx = tid & 15, ry = tid >> 4;
  int cb = jt*64;
  int wdd = tid >> 4, wseg = tid & 15;
  int xrow = tid >> 3, xseg = tid & 7;

  __shared__ float Wt0[32][64], Wt1[32][64];
  __shared__ float Xt0[32][68], Xt1[32][68];

  float acc[4][4];
  #pragma unroll
  for (int cc=0;cc<4;++cc)
    #pragma unroll
    for (int rr=0;rr<4;++rr) acc[cc][rr]=0.f;

  int d0 = ks*128;
  const float* xp0 = x + (size_t)xrow*D2 + d0 + xseg*4;
  const float* xp1 = x + (size_t)(xrow+32)*D2 + d0 + xseg*4;

#define GLQ(WA,WB,X0,X1, ch) { int d_ = d0 + (ch)*32; \
  WA = GWLD(d_+wdd,    cb+wseg*4); \
  WB = GWLD(d_+16+wdd, cb+wseg*4); \
  X0 = *(const float4*)(xp0 + (ch)*32); \
  X1 = *(const float4*)(xp1 + (ch)*32); }
#define GSQ(Wt,Xt, WA,WB,X0,X1) { \
  *(float4*)&Wt[wdd][wseg*4]    = WA; \
  *(float4*)&Wt[wdd+16][wseg*4] = WB; \
  Xt[xseg*4+0][xrow] = X0.x; Xt[xseg*4+1][xrow] = X0.y; \
  Xt[xseg*4+2][xrow] = X0.z; Xt[xseg*4+3][xrow] = X0.w; \
  Xt[xseg*4+0][xrow+32] = X1.x; Xt[xseg*4+1][xrow+32] = X1.y; \
  Xt[xseg*4+2][xrow+32] = X1.z; Xt[xseg*4+3][xrow+32] = X1.w; }
#define GCQ(Wt,Xt) { _Pragma("unroll 8") for (int dd=0; dd<32; ++dd){ \
    float4 w4 = *(const float4*)&Wt[dd][cx*4]; \
    float4 h4 = *(const float4*)&Xt[dd][ry*4]; \
    FMA16(w4, h4) } }

  float4 wA0,wB0,x00,x10, wA1,wB1,x01,x11;
  GLQ(wA0,wB0,x00,x10, 0)
  GSQ(Wt0,Xt0, wA0,wB0,x00,x10)
  GLQ(wA1,wB1,x01,x11, 1)
  __syncthreads();

  for (int ch=0; ch<4; ch+=2){
    if (ch+2<4) GLQ(wA0,wB0,x00,x10, ch+2)
    GSQ(Wt1,Xt1, wA1,wB1,x01,x11)
    GCQ(Wt0,Xt0)
    __syncthreads();
    if (ch+3<4) GLQ(wA1,wB1,x01,x11, ch+3)
    if (ch+2<4) GSQ(Wt0,Xt0, wA0,wB0,x00,x10)
    GCQ(Wt1,Xt1)
    if (ch+2<4) __syncthreads();
  }
  #pragma unroll
  for (int rr=0;rr<4;++rr){
    float4 o; o.x=acc[0][rr]; o.y=acc[1][rr]; o.z=acc[2][rr]; o.w=acc[3][rr];
    *(float4*)&gpart[((size_t)(ks*R_N + ry*4+rr))*4096 + cb + cx*4] = o;
  }
}

// ---- LSTM: sum partials + bias, cell update; h2 -> xn, h2t, and fp16 splits.
// grid (64 rows x 4 H-quarters), 256 thr.
__global__ __launch_bounds__(256) void k_lstm(
    const float* __restrict__ gpart, const float* __restrict__ b_lstm,
    float* __restrict__ c, float* __restrict__ xn, float* __restrict__ h2t,
    f16* __restrict__ hhi, f16* __restrict__ hlo){
  int r = blockIdx.x, tid = threadIdx.x;
  int j = blockIdx.y*256 + tid;
  float gi = b_lstm[j], gf = b_lstm[1024+j], gg = b_lstm[2048+j], go = b_lstm[3072+j];
  #pragma unroll
  for (int ds=0; ds<NDS; ++ds){
    size_t base = ((size_t)ds*R_N + r)*4096;
    gi += gpart[base + j];      gf += gpart[base + 1024 + j];
    gg += gpart[base + 2048+j]; go += gpart[base + 3072 + j];
  }
  float cv = c[(size_t)r*H_N + j];
  float c2 = sigmf(gf)*cv + sigmf(gi)*tanhf(gg);
  float h2 = sigmf(go)*tanhf(c2);
  c[(size_t)r*H_N + j] = c2;
  xn[(size_t)r*D2 + DIN + j] = h2;
  h2t[(size_t)j*R_N + r] = h2;
  f16 hh = (f16)h2;
  hhi[(size_t)r*H_N + j] = hh;
  hlo[(size_t)r*H_N + j] = (f16)((h2 - (float)hh)*4096.0f);
}

// ---- logits via MFMA fp16-split: grid 500 x 256 (4 waves; wave = 16 vocab x
// 64 rows x K=1024). No LDS, no barriers. 12 MFMA + 10 x 16B loads per K=32.
// logit = acc1 + acc2/4096;  acc1 = whi*hhi, acc2 = wlo*hhi + whi*hlo.
__global__ __launch_bounds__(256) void k_logits_mfma(
    const f16* __restrict__ whi, const f16* __restrict__ wlo,
    const f16* __restrict__ hhi, const f16* __restrict__ hlo,
    float* __restrict__ plog){
  int tid = threadIdx.x;
  int lane = tid & 63;
  int wv = tid >> 6;
  int vb = blockIdx.x*64 + wv*16;
  int lm = lane & 15;
  int lk = (lane >> 4) * 8;

  const f16* wph = whi + (size_t)(vb + lm)*1024 + lk;
  const f16* wpl = wlo + (size_t)(vb + lm)*1024 + lk;
  const f16* hh  = hhi + (size_t)lm*1024 + lk;
  const f16* hl  = hlo + (size_t)lm*1024 + lk;

  f32x4 c10={0,0,0,0}, c11={0,0,0,0}, c12={0,0,0,0}, c13={0,0,0,0};
  f32x4 c20={0,0,0,0}, c21={0,0,0,0}, c22={0,0,0,0}, c23={0,0,0,0};

  f16x8 Bh0,Bl0,A0h0,A1h0,A2h0,A3h0,A0l0,A1l0,A2l0,A3l0;
  f16x8 Bh1,Bl1,A0h1,A1h1,A2h1,A3h1,A0l1,A1l1,A2l1,A3l1;

#define LOADSET(S, ks) { int o_ = (ks)*32; \
  Bh##S = *(const f16x8*)(wph + o_); Bl##S = *(const f16x8*)(wpl + o_); \
  A0h##S = *(const f16x8*)(hh + o_);            A0l##S = *(const f16x8*)(hl + o_); \
  A1h##S = *(const f16x8*)(hh + 16*1024 + o_);  A1l##S = *(const f16x8*)(hl + 16*1024 + o_); \
  A2h##S = *(const f16x8*)(hh + 32*1024 + o_);  A2l##S = *(const f16x8*)(hl + 32*1024 + o_); \
  A3h##S = *(const f16x8*)(hh + 48*1024 + o_);  A3l##S = *(const f16x8*)(hl + 48*1024 + o_); }
#define COMPSET(S) { \
  c10 = MFMA(A0h##S, Bh##S, c10); c20 = MFMA(A0l##S, Bh##S, c20); c20 = MFMA(A0h##S, Bl##S, c20); \
  c11 = MFMA(A1h##S, Bh##S, c11); c21 = MFMA(A1l##S, Bh##S, c21); c21 = MFMA(A1h##S, Bl##S, c21); \
  c12 = MFMA(A2h##S, Bh##S, c12); c22 = MFMA(A2l##S, Bh##S, c22); c22 = MFMA(A2h##S, Bl##S, c22); \
  c13 = MFMA(A3h##S, Bh##S, c13); c23 = MFMA(A3l##S, Bh##S, c23); c23 = MFMA(A3h##S, Bl##S, c23); }

  LOADSET(0, 0)
  for (int ks=0; ks<32; ks+=2){
    LOADSET(1, ks+1)
    COMPSET(0)
    if (ks+2<32) LOADSET(0, ks+2)
    COMPSET(1)
  }

  const float inv = 1.0f/4096.0f;
  int rb = (lane>>4)*4;
#define STT(mt, A1, A2) { \
  _Pragma("unroll") for (int rg=0; rg<4; ++rg){ \
    plog[(size_t)((mt)*16 + rb + rg)*V_N + vb + lm] = A1[rg] + A2[rg]*inv; } }
  STT(0, c10, c20) STT(1, c11, c21) STT(2, c12, c22) STT(3, c13, c23)
}

// ---- stats: bias + per-row softmax stats & top-4 from plog[64][32000].
__global__ __launch_bounds__(256) void k_stats(
    const float* __restrict__ plog, const float* __restrict__ b_out,
    float* __restrict__ pm, float* __restrict__ pz,
    float* __restrict__ pv, int* __restrict__ pi){
  int tid = threadIdx.x;
  int cx = tid & 15, ry = tid >> 4;
  int cb = blockIdx.x * 64;
  float4 bias = *(const float4*)&b_out[cb + cx*4];
  #pragma unroll
  for (int rr=0;rr<4;++rr){
    int row = ry*4 + rr;
    float4 a = *(const float4*)&plog[(size_t)row*V_N + cb + cx*4];
    float v0 = a.x+bias.x, v1 = a.y+bias.y;
    float v2 = a.z+bias.z, v3 = a.w+bias.w;
    int   c0i = cb + cx*4;
    float tv0=-INFINITY,tv1=-INFINITY,tv2=-INFINITY,tv3=-INFINITY;
    int   ti0=0x7fffffff,ti1=0x7fffffff,ti2=0x7fffffff,ti3=0x7fffffff;
    ins4(v0,c0i+0,tv0,tv1,tv2,tv3,ti0,ti1,ti2,ti3);
    ins4(v1,c0i+1,tv0,tv1,tv2,tv3,ti0,ti1,ti2,ti3);
    ins4(v2,c0i+2,tv0,tv1,tv2,tv3,ti0,ti1,ti2,ti3);
    ins4(v3,c0i+3,tv0,tv1,tv2,tv3,ti0,ti1,ti2,ti3);
    float z = expf(v0-tv0)+expf(v1-tv0)+expf(v2-tv0)+expf(v3-tv0);
    #pragma unroll
    for (int msk=1; msk<16; msk<<=1){
      float om  = __shfl_xor(tv0, msk, 16);
      float oz  = __shfl_xor(z,   msk, 16);
      float ov1 = __shfl_xor(tv1, msk, 16);
      float ov2 = __shfl_xor(tv2, msk, 16);
      float ov3 = __shfl_xor(tv3, msk, 16);
      int   oi0 = __shfl_xor(ti0, msk, 16);
      int   oi1 = __shfl_xor(ti1, msk, 16);
      int   oi2 = __shfl_xor(ti2, msk, 16);
      int   oi3 = __shfl_xor(ti3, msk, 16);
      float M = fmaxf(tv0, om);
      z = z*expf(tv0-M) + oz*expf(om-M);
      ins4(om, oi0, tv0,tv1,tv2,tv3, ti0,ti1,ti2,ti3);
      ins4(ov1,oi1, tv0,tv1,tv2,tv3, ti0,ti1,ti2,ti3);
      ins4(ov2,oi2, tv0,tv1,tv2,tv3, ti0,ti1,ti2,ti3);
      ins4(ov3,oi3, tv0,tv1,tv2,tv3, ti0,ti1,ti2,ti3);
    }
    if (cx == 0){
      size_t base = (size_t)row*NB + blockIdx.x;
      pm[base]=tv0; pz[base]=z;
      pv[base*4+0]=tv0; pv[base*4+1]=tv1; pv[base*4+2]=tv2; pv[base*4+3]=tv3;
      pi[base*4+0]=ti0; pi[base*4+1]=ti1; pi[base*4+2]=ti2; pi[base*4+3]=ti3;
    }
  }
}

// ---- fallback: fused fp32 logits+stats (round-6 kernel), if ws too small.
__global__ __launch_bounds__(256) void k_logits_fused(
    const float* __restrict__ h2t, const float* __restrict__ w_out,
    const float* __restrict__ b_out,
    float* __restrict__ pm, float* __restrict__ pz,
    float* __restrict__ pv, int* __restrict__ pi){
  int tid = threadIdx.x;
  int cx  = tid & 15, ry = tid >> 4;
  int cb  = blockIdx.x * 64;
  int sdd = tid >> 4, seg = tid & 15;
  __shared__ float Wt[32][64];
  __shared__ float Ht[32][64];
  float acc[4][4];
  #pragma unroll
  for (int cc=0;cc<4;++cc)
    #pragma unroll
    for (int rr=0;rr<4;++rr) acc[cc][rr]=0.f;
  const float* gW = w_out + (size_t)sdd*V_N + cb + seg*4;
  const float* gH = h2t + sdd*64 + seg*4;
#define FLQ(WA,WB,HA,HB, ch) { \
  const float* gWn = gW + (size_t)(ch)*32*V_N; \
  const float* gHn = gH + (size_t)(ch)*32*64; \
  WA = *(const float4*)gWn; WB = *(const float4*)(gWn + (size_t)16*V_N); \
  HA = *(const float4*)gHn; HB = *(const float4*)(gHn + 16*64); }
#define FSQ(WA,WB,HA,HB) { \
  *(float4*)&Wt[sdd][seg*4]    = WA; \
  *(float4*)&Wt[sdd+16][seg*4] = WB; \
  *(float4*)&Ht[sdd][seg*4]    = HA; \
  *(float4*)&Ht[sdd+16][seg*4] = HB; }
#define FCQ() { _Pragma("unroll 8") for (int dd=0; dd<32; ++dd){ \
    float4 w4 = *(const float4*)&Wt[dd][cx*4]; \
    float4 h4 = *(const float4*)&Ht[dd][ry*4]; \
    FMA16(w4, h4) } }
  float4 wA0,wB0,hA0,hB0, wA1,wB1,hA1,hB1;
  FLQ(wA0,wB0,hA0,hB0, 0)
  FSQ(wA0,wB0,hA0,hB0)
  FLQ(wA1,wB1,hA1,hB1, 1)
  __syncthreads();
  for (int ch=0; ch<32; ch+=2){
    if (ch+2<32) FLQ(wA0,wB0,hA0,hB0, ch+2)
    FCQ()
    __syncthreads();
    FSQ(wA1,wB1,hA1,hB1)
    __syncthreads();
    if (ch+3<32) FLQ(wA1,wB1,hA1,hB1, ch+3)
    FCQ()
    if (ch+2<32){
      __syncthreads();
      FSQ(wA0,wB0,hA0,hB0)
      __syncthreads();
    }
  }
  float4 bias = *(const float4*)&b_out[cb + cx*4];
  #pragma unroll
  for (int rr=0;rr<4;++rr){
    float v0 = acc[0][rr]+bias.x, v1 = acc[1][rr]+bias.y;
    float v2 = acc[2][rr]+bias.z, v3 = acc[3][rr]+bias.w;
    int   c0i = cb + cx*4;
    float tv0=-INFINITY,tv1=-INFINITY,tv2=-INFINITY,tv3=-INFINITY;
    int   ti0=0x7fffffff,ti1=0x7fffffff,ti2=0x7fffffff,ti3=0x7fffffff;
    ins4(v0,c0i+0,tv0,tv1,tv2,tv3,ti0,ti1,ti2,ti3);
    ins4(v1,c0i+1,tv0,tv1,tv2,tv3,ti0,ti1,ti2,ti3);
    ins4(v2,c0i+2,tv0,tv1,tv2,tv3,ti0,ti1,ti2,ti3);
    ins4(v3,c0i+3,tv0,tv1,tv2,tv3,ti0,ti1,ti2,ti3);
    float z = expf(v0-tv0)+expf(v1-tv0)+expf(v2-tv0)+expf(v3-tv0);
    #pragma unroll
    for (int msk=1; msk<16; msk<<=1){
      float om  = __shfl_xor(tv0, msk, 16);
      float oz  = __shfl_xor(z,   msk, 16);
      float ov1 = __shfl_xor(tv1, msk, 16);
      float ov2 = __shfl_xor(tv2, msk, 16);
      float ov3 = __shfl_xor(tv3, msk, 16);
      int   oi0 = __shfl_xor(ti0, msk, 16);
      int   oi1 = __shfl_xor(ti1, msk, 16);
      int   oi2 = __shfl_xor(ti2, msk, 16);
      int   oi3 = __shfl_xor(ti3, msk, 16);
      float M = fmaxf(tv0, om);
      z = z*expf(tv0-M) + oz*expf(om-M);
      ins4(om, oi0, tv0,tv1,tv2,tv3, ti0,ti1,ti2,ti3);
      ins4(ov1,oi1, tv0,tv1,tv2,tv3, ti0,ti1,ti2,ti3);
      ins4(ov2,oi2, tv0,tv1,tv2,tv3, ti0,ti1,ti2,ti3);
      ins4(ov3,oi3, tv0,tv1,tv2,tv3, ti0,ti1,ti2,ti3);
    }
    if (cx == 0){
      int row = ry*4 + rr;
      size_t base = (size_t)row*NB + blockIdx.x;
      pm[base]=tv0; pz[base]=z;
      pv[base*4+0]=tv0; pv[base*4+1]=tv1; pv[base*4+2]=tv2; pv[base*4+3]=tv3;
      pi[base*4+0]=ti0; pi[base*4+1]=ti1; pi[base*4+2]=ti2; pi[base*4+3]=ti3;
    }
  }
}

// ---- final: per-beam wave reduce + joint top-4 + next-x assembly.
__global__ __launch_bounds__(256) void k_final(
    const float* __restrict__ pm, const float* __restrict__ pz,
    const float* __restrict__ pv, const int* __restrict__ pi,
    float* __restrict__ scores, int* __restrict__ out, int t,
    float* __restrict__ xn,
    const float* __restrict__ enc_inputs, const float* __restrict__ enc_outputs,
    const float* __restrict__ embed){
  int b = blockIdx.x, tid = threadIdx.x;
  int kk = tid >> 6, lane = tid & 63;
  __shared__ float fM[KBEAM], fZ[KBEAM], fV[16];
  __shared__ int   fI[16], sw[KBEAM];
  int nk = (t==0) ? 1 : KBEAM;
  if (kk < nk){
    size_t rb = (size_t)(kk*B_N + b)*NB;
    float m=-INFINITY, z=0.f;
    float av0=-INFINITY,av1=-INFINITY,av2=-INFINITY,av3=-INFINITY;
    int   ai0=0x7fffffff,ai1=0x7fffffff,ai2=0x7fffffff,ai3=0x7fffffff;
    for (int p0=lane; p0<NB; p0+=64){
      size_t p = rb + p0;
      float mf = pm[p];
      float M = fmaxf(m, mf);
      z = z*expf(m-M) + pz[p]*expf(mf-M);
      m = M;
      #pragma unroll
      for (int q=0;q<4;++q)
        ins4(pv[p*4+q], pi[p*4+q], av0,av1,av2,av3, ai0,ai1,ai2,ai3);
    }
    #pragma unroll
    for (int msk=1; msk<64; msk<<=1){
      float om  = __shfl_xor(m,   msk);
      float oz  = __shfl_xor(z,   msk);
      float ov0 = __shfl_xor(av0, msk);
      float ov1 = __shfl_xor(av1, msk);
      float ov2 = __shfl_xor(av2, msk);
      float ov3 = __shfl_xor(av3, msk);
      int   oi0 = __shfl_xor(ai0, msk);
      int   oi1 = __shfl_xor(ai1, msk);
      int   oi2 = __shfl_xor(ai2, msk);
      int   oi3 = __shfl_xor(ai3, msk);
      float M = fmaxf(m, om);
      z = z*expf(m-M) + oz*expf(om-M);
      m = M;
      ins4(ov0,oi0, av0,av1,av2,av3, ai0,ai1,ai2,ai3);
      ins4(ov1,oi1, av0,av1,av2,av3, ai0,ai1,ai2,ai3);
      ins4(ov2,oi2, av0,av1,av2,av3, ai0,ai1,ai2,ai3);
      ins4(ov3,oi3, av0,av1,av2,av3, ai0,ai1,ai2,ai3);
    }
    if (lane == 0){
      fM[kk]=m; fZ[kk]=z;
      fV[kk*4+0]=av0; fV[kk*4+1]=av1; fV[kk*4+2]=av2; fV[kk*4+3]=av3;
      fI[kk*4+0]=ai0; fI[kk*4+1]=ai1; fI[kk*4+2]=ai2; fI[kk*4+3]=ai3;
    }
  }
  __syncthreads();
  if (tid==0){
    if (t==0){
      #pragma unroll
      for (int j=0;j<4;++j){
        float p = expf(fV[j]-fM[0])/fZ[0];
        scores[b*4+j] = p;
        out[j*(B_N*S_LEN) + b*S_LEN] = fI[j];
        sw[j] = fI[j];
      }
    } else {
      float cv[16]; int cj[16];
      for (int k=0;k<4;++k){
        float s = scores[b*4+k];
        #pragma unroll
        for (int j=0;j<4;++j){
          cv[k*4+j] = expf(fV[k*4+j]-fM[k])/fZ[k]*s;
          cj[k*4+j] = k*V_N + fI[k*4+j];
        }
      }
      bool used[16];
      for (int i=0;i<16;++i) used[i]=false;
      for (int rank=0;rank<4;++rank){
        int best=-1;
        for (int i=0;i<16;++i){
          if (used[i]) continue;
          if (best<0 || cv[i]>cv[best] || (cv[i]==cv[best] && cj[i]<cj[best])) best=i;
        }
        used[best]=true;
        out[rank*(B_N*S_LEN) + b*S_LEN + t] = cj[best];
        sw[rank] = cj[best] % V_N;
      }
    }
  }
  __syncthreads();
  if (t < S_LEN-1){
    const float* ein = enc_inputs  + (size_t)(t+1)*B_N*E_N + (size_t)b*E_N;
    const float* eo  = enc_outputs + (size_t)(t+1)*B_N*H_N + (size_t)b*H_N;
    #pragma unroll
    for (int j=0;j<KBEAM;++j){
      float* xr = xn + (size_t)(j*B_N + b)*D2;
      const float* em = embed + (size_t)sw[j]*E_N;
      xr[tid]       = em[tid];
      xr[E_N + tid] = ein[tid];
      #pragma unroll
      for (int q=0;q<4;++q) xr[2*E_N + q*256 + tid] = eo[q*256 + tid];
    }
  }
}

extern "C" void kernel_launch(void* const* d_in, const int* in_sizes, int n_in,
                              void* d_out, int out_size, void* d_ws, size_t ws_size,
                              hipStream_t stream) {
  (void)in_sizes; (void)n_in; (void)out_size;
  const float* enc_h_n     = (const float*)d_in[0];
  const float* enc_c_n     = (const float*)d_in[1];
  const float* enc_outputs = (const float*)d_in[2];
  const float* enc_inputs  = (const float*)d_in[3];
  const float* embed       = (const float*)d_in[4];
  const float* w_ih        = (const float*)d_in[5];
  const float* w_hh        = (const float*)d_in[6];
  const float* b_lstm      = (const float*)d_in[7];
  const float* w_out       = (const float*)d_in[8];
  const float* b_out       = (const float*)d_in[9];
  int* out = (int*)d_out;

  float* ws = (float*)d_ws;
  const size_t FRONTF = (size_t)R_N*D2*2 + (size_t)R_N*H_N + (size_t)H_N*R_N; // 458752
  const size_t HSPLF  = (size_t)R_N*H_N;        // 65536 floats (2 x fp16 arrays)
  const size_t PLOGF  = (size_t)R_N*V_N;        // 2,048,000
  const size_t GPARTF = (size_t)NDS*R_N*4096;   // 5,242,880
  const size_t STATF  = (size_t)R_N*NB*10;      // 320,000
  const size_t WSPLF  = (size_t)V_N*H_N;        // 32,768,000 floats (2 x fp16 arrays)
  size_t bigF = (PLOGF > GPARTF ? PLOGF : GPARTF);
  size_t need_split = (FRONTF + HSPLF + bigF + STATF + 64 + WSPLF)*sizeof(float);
  bool use_split = (ws_size >= need_split);

  float* xA     = ws;
  float* xB     = xA + (size_t)R_N*D2;
  float* cbuf   = xB + (size_t)R_N*D2;
  float* h2t    = cbuf + (size_t)R_N*H_N;
  f16*   hhi    = (f16*)(h2t + (size_t)H_N*R_N);
  f16*   hlo    = hhi + (size_t)R_N*H_N;
  float* big    = h2t + (size_t)H_N*R_N + HSPLF;
  float* gpart  = big;                       // lifetime: k_gates -> k_lstm
  float* plog   = big;                       // lifetime: k_logits_mfma -> k_stats
  float* pm     = big + bigF;
  float* pz     = pm + (size_t)R_N*NB;
  float* pv     = pz + (size_t)R_N*NB;
  int*   pi     = (int*)(pv + (size_t)R_N*NB*4);
  float* scoresb= (float*)(pi + (size_t)R_N*NB*4);
  f16*   whi    = (f16*)(scoresb + 64);
  f16*   wlo    = whi + (size_t)V_N*H_N;

  if (use_split){
    k_convw<<<dim3(V_N/64, H_N/64), 256, 0, stream>>>(w_out, whi, wlo);
  }
  k_init<<<R_N, 256, 0, stream>>>(enc_h_n, enc_c_n, enc_outputs, enc_inputs, embed, xA, cbuf);

  for (int t=0; t<S_LEN; ++t){
    float* xc = (t & 1) ? xB : xA;
    float* xn = (t & 1) ? xA : xB;
    k_gates <<<dim3(64, NDS), 256, 0, stream>>>(xc, w_ih, w_hh, gpart);
    k_lstm  <<<dim3(R_N, 4), 256, 0, stream>>>(gpart, b_lstm, cbuf, xn, h2t, hhi, hlo);
    if (use_split){
      k_logits_mfma<<<V_N/64, 256, 0, stream>>>(whi, wlo, hhi, hlo, plog);
      k_stats<<<NB, 256, 0, stream>>>(plog, b_out, pm, pz, pv, pi);
    } else {
      k_logits_fused<<<NB, 256, 0, stream>>>(h2t, w_out, b_out, pm, pz, pv, pi);
    }
    k_final <<<B_N, 256, 0, stream>>>(pm, pz, pv, pi, scoresb, out, t, xn,
                                      enc_inputs, enc_outputs, embed);
  }
}

// Round 19
// 3109.183 us; speedup vs baseline: 1.4227x; 1.4227x over previous
//
#include <hip/hip_runtime.h>
#include <math.h>

#define S_LEN 32
#define B_N   16
#define H_N   1024
#define E_N   256
#define V_N   32000
#define KBEAM 4
#define DIN   1536
#define D2    2560   // DIN + H_N
#define R_N   64     // KBEAM * B_N rows of state
#define NDS   20     // K-slices for gates GEMM (128 each, 4 chunks)
#define NB    500    // stats/final col-blocks = V_N/64
#define LKS   2      // logits K-split (16 slices of 32 each)

typedef _Float16 f16;
typedef f16   f16x8 __attribute__((ext_vector_type(8)));
typedef float f32x4 __attribute__((ext_vector_type(4)));
#define MFMA(A,B,C) __builtin_amdgcn_mfma_f32_16x16x32_f16(A,B,C,0,0,0)

__device__ __forceinline__ float sigmf(float x){ return 1.0f/(1.0f+expf(-x)); }
__device__ __forceinline__ bool better(float v1,int i1,float v2,int i2){
  return (v1>v2) || (v1==v2 && i1<i2);
}
__device__ __forceinline__ void ins4(float bv,int bi,
    float&av0,float&av1,float&av2,float&av3,int&ai0,int&ai1,int&ai2,int&ai3){
  if (better(bv,bi,av3,ai3)){ av3=bv; ai3=bi;
    if (better(av3,ai3,av2,ai2)){ float t=av2;av2=av3;av3=t; int q=ai2;ai2=ai3;ai3=q;
      if (better(av2,ai2,av1,ai1)){ t=av1;av1=av2;av2=t; q=ai1;ai1=ai2;ai2=q;
        if (better(av1,ai1,av0,ai0)){ t=av0;av0=av1;av1=t; q=ai0;ai0=ai1;ai1=q; } } } }
}

#define FMA16(w4, h4) { \
  acc[0][0]=fmaf(w4.x,h4.x,acc[0][0]); acc[0][1]=fmaf(w4.x,h4.y,acc[0][1]); \
  acc[0][2]=fmaf(w4.x,h4.z,acc[0][2]); acc[0][3]=fmaf(w4.x,h4.w,acc[0][3]); \
  acc[1][0]=fmaf(w4.y,h4.x,acc[1][0]); acc[1][1]=fmaf(w4.y,h4.y,acc[1][1]); \
  acc[1][2]=fmaf(w4.y,h4.z,acc[1][2]); acc[1][3]=fmaf(w4.y,h4.w,acc[1][3]); \
  acc[2][0]=fmaf(w4.z,h4.x,acc[2][0]); acc[2][1]=fmaf(w4.z,h4.y,acc[2][1]); \
  acc[2][2]=fmaf(w4.z,h4.z,acc[2][2]); acc[2][3]=fmaf(w4.z,h4.w,acc[2][3]); \
  acc[3][0]=fmaf(w4.w,h4.x,acc[3][0]); acc[3][1]=fmaf(w4.w,h4.y,acc[3][1]); \
  acc[3][2]=fmaf(w4.w,h4.z,acc[3][2]); acc[3][3]=fmaf(w4.w,h4.w,acc[3][3]); }

__global__ __launch_bounds__(256) void k_init(
    const float* __restrict__ enc_h_n, const float* __restrict__ enc_c_n,
    const float* __restrict__ enc_outputs, const float* __restrict__ enc_inputs,
    const float* __restrict__ embed, float* __restrict__ x, float* __restrict__ c){
  int r = blockIdx.x, tid = threadIdx.x, b = r & 15;
  float* xr = x + (size_t)r*D2;
  xr[tid]        = embed[E_N + tid];
  xr[E_N + tid]  = enc_inputs[b*E_N + tid];
  #pragma unroll
  for (int q=0;q<4;++q) xr[2*E_N + q*256 + tid] = enc_outputs[b*H_N + q*256 + tid];
  #pragma unroll
  for (int q=0;q<4;++q) xr[DIN + q*256 + tid]   = enc_h_n[b*H_N + q*256 + tid];
  #pragma unroll
  for (int q=0;q<4;++q) c[(size_t)r*H_N + q*256 + tid] = enc_c_n[b*H_N + q*256 + tid];
}

// ---- one-time: transpose + fp16-split + fragment-pack w_out -> wpk.
__global__ __launch_bounds__(256) void k_convw(
    const float* __restrict__ w, f16* __restrict__ wpk){
  __shared__ f16 Th[64][66];
  __shared__ f16 Tl[64][66];
  int v0 = blockIdx.x*64, d0 = blockIdx.y*64;
  int tid = threadIdx.x;
  int r = tid >> 4, cq = (tid & 15)*4;
  #pragma unroll
  for (int rr=0; rr<4; ++rr){
    int d = r + rr*16;
    float4 x = *(const float4*)&w[(size_t)(d0+d)*V_N + v0 + cq];
    f16 h;
    h=(f16)x.x; Th[d][cq+0]=h; Tl[d][cq+0]=(f16)((x.x-(float)h)*4096.0f);
    h=(f16)x.y; Th[d][cq+1]=h; Tl[d][cq+1]=(f16)((x.y-(float)h)*4096.0f);
    h=(f16)x.z; Th[d][cq+2]=h; Tl[d][cq+2]=(f16)((x.z-(float)h)*4096.0f);
    h=(f16)x.w; Th[d][cq+3]=h; Tl[d][cq+3]=(f16)((x.w-(float)h)*4096.0f);
  }
  __syncthreads();
  int T2 = tid >> 6, l = tid & 63;
  int lm = l & 15, kq = l >> 4;
  int Tg = blockIdx.x*4 + T2;
  #pragma unroll
  for (int ks2=0; ks2<2; ++ks2){
    int ksg = blockIdx.y*2 + ks2;
    f16x8 a, b2;
    #pragma unroll
    for (int i=0;i<8;++i){
      int dd = ks2*32 + kq*8 + i;
      a[i]  = Th[dd][T2*16 + lm];
      b2[i] = Tl[dd][T2*16 + lm];
    }
    size_t base = ((size_t)(Tg*32 + ksg)*2)*512 + l*8;
    *(f16x8*)&wpk[base]       = a;
    *(f16x8*)&wpk[base + 512] = b2;
  }
}

#define GWLD(d, off) (*(const float4*)((((d) < DIN) ? (w_ih + (size_t)(d)*4096) \
                       : (w_hh + (size_t)((d)-DIN)*4096)) + (off)))
__global__ __launch_bounds__(256) void k_gates(
    const float* __restrict__ x, const float* __restrict__ w_ih,
    const float* __restrict__ w_hh, float* __restrict__ gpart){
  int tid = threadIdx.x;
  int jt = blockIdx.x, ks = blockIdx.y;
  int cx = tid & 15, ry = tid >> 4;
  int cb = jt*64;
  int wdd = tid >> 4, wseg = tid & 15;
  int xrow = tid >> 3, xseg = tid & 7;

  __shared__ float Wt0[32][64], Wt1[32][64];
  __shared__ float Xt0[32][68], Xt1[32][68];

  float acc[4][4];
  #pragma unroll
  for (int cc=0;cc<4;++cc)
    #pragma unroll
    for (int rr=0;rr<4;++rr) acc[cc][rr]=0.f;

  int d0 = ks*128;
  const float* xp0 = x + (size_t)xrow*D2 + d0 + xseg*4;
  const float* xp1 = x + (size_t)(xrow+32)*D2 + d0 + xseg*4;

#define GLQ(WA,WB,X0,X1, ch) { int d_ = d0 + (ch)*32; \
  WA = GWLD(d_+wdd,    cb+wseg*4); \
  WB = GWLD(d_+16+wdd, cb+wseg*4); \
  X0 = *(const float4*)(xp0 + (ch)*32); \
  X1 = *(const float4*)(xp1 + (ch)*32); }
#define GSQ(Wt,Xt, WA,WB,X0,X1) { \
  *(float4*)&Wt[wdd][wseg*4]    = WA; \
  *(float4*)&Wt[wdd+16][wseg*4] = WB; \
  Xt[xseg*4+0][xrow] = X0.x; Xt[xseg*4+1][xrow] = X0.y; \
  Xt[xseg*4+2][xrow] = X0.z; Xt[xseg*4+3][xrow] = X0.w; \
  Xt[xseg*4+0][xrow+32] = X1.x; Xt[xseg*4+1][xrow+32] = X1.y; \
  Xt[xseg*4+2][xrow+32] = X1.z; Xt[xseg*4+3][xrow+32] = X1.w; }
#define GCQ(Wt,Xt) { _Pragma("unroll 8") for (int dd=0; dd<32; ++dd){ \
    float4 w4 = *(const float4*)&Wt[dd][cx*4]; \
    float4 h4 = *(const float4*)&Xt[dd][ry*4]; \
    FMA16(w4, h4) } }

  float4 wA0,wB0,x00,x10, wA1,wB1,x01,x11;
  GLQ(wA0,wB0,x00,x10, 0)
  GSQ(Wt0,Xt0, wA0,wB0,x00,x10)
  GLQ(wA1,wB1,x01,x11, 1)
  __syncthreads();

  for (int ch=0; ch<4; ch+=2){
    if (ch+2<4) GLQ(wA0,wB0,x00,x10, ch+2)
    GSQ(Wt1,Xt1, wA1,wB1,x01,x11)
    GCQ(Wt0,Xt0)
    __syncthreads();
    if (ch+3<4) GLQ(wA1,wB1,x01,x11, ch+3)
    if (ch+2<4) GSQ(Wt0,Xt0, wA0,wB0,x00,x10)
    GCQ(Wt1,Xt1)
    if (ch+2<4) __syncthreads();
  }
  #pragma unroll
  for (int rr=0;rr<4;++rr){
    float4 o; o.x=acc[0][rr]; o.y=acc[1][rr]; o.z=acc[2][rr]; o.w=acc[3][rr];
    *(float4*)&gpart[((size_t)(ks*R_N + ry*4+rr))*4096 + cb + cx*4] = o;
  }
}

__global__ __launch_bounds__(256) void k_lstm(
    const float* __restrict__ gpart, const float* __restrict__ b_lstm,
    float* __restrict__ c, float* __restrict__ xn, float* __restrict__ h2t,
    f16* __restrict__ hpk){
  int r = blockIdx.x, tid = threadIdx.x;
  int j = blockIdx.y*256 + tid;
  float gi = b_lstm[j], gf = b_lstm[1024+j], gg = b_lstm[2048+j], go = b_lstm[3072+j];
  #pragma unroll
  for (int ds=0; ds<NDS; ++ds){
    size_t base = ((size_t)ds*R_N + r)*4096;
    gi += gpart[base + j];      gf += gpart[base + 1024 + j];
    gg += gpart[base + 2048+j]; go += gpart[base + 3072 + j];
  }
  float cv = c[(size_t)r*H_N + j];
  float c2 = sigmf(gf)*cv + sigmf(gi)*tanhf(gg);
  float h2 = sigmf(go)*tanhf(c2);
  c[(size_t)r*H_N + j] = c2;
  xn[(size_t)r*D2 + DIN + j] = h2;
  h2t[(size_t)j*R_N + r] = h2;
  f16 hh = (f16)h2;
  int m = r >> 4, lm = r & 15;
  int ks = j >> 5, kq = (j & 31) >> 3, i = j & 7;
  int l = lm + 16*kq;
  size_t base2 = ((size_t)(m*32 + ks)*2)*512 + l*8 + i;
  hpk[base2]       = hh;
  hpk[base2 + 512] = (f16)((h2 - (float)hh)*4096.0f);
}

__global__ __launch_bounds__(256) void k_logits_mfma(
    const f16* __restrict__ wpk, const f16* __restrict__ hpk,
    float* __restrict__ plog){
  int tid = threadIdx.x;
  int lane = tid & 63;
  int wv = tid >> 6;
  int T  = blockIdx.x*4 + wv;
  int vb = T*16;
  int ksb = blockIdx.y*16;

  const f16* wp  = wpk + ((size_t)(T*32 + ksb)*2)*512 + lane*8;
  const f16* hp0 = hpk + ((size_t)(0*32 + ksb)*2)*512 + lane*8;
  const f16* hp1 = hpk + ((size_t)(1*32 + ksb)*2)*512 + lane*8;
  const f16* hp2 = hpk + ((size_t)(2*32 + ksb)*2)*512 + lane*8;
  const f16* hp3 = hpk + ((size_t)(3*32 + ksb)*2)*512 + lane*8;

  f32x4 c10={0,0,0,0}, c11={0,0,0,0}, c12={0,0,0,0}, c13={0,0,0,0};
  f32x4 c20={0,0,0,0}, c21={0,0,0,0}, c22={0,0,0,0}, c23={0,0,0,0};

  f16x8 Bh0,Bl0,A0h0,A1h0,A2h0,A3h0,A0l0,A1l0,A2l0,A3l0;
  f16x8 Bh1,Bl1,A0h1,A1h1,A2h1,A3h1,A0l1,A1l1,A2l1,A3l1;

#define LOADSET(S, s) { size_t o_ = (size_t)(s)*1024; \
  Bh##S  = *(const f16x8*)(wp + o_);  Bl##S  = *(const f16x8*)(wp + o_ + 512); \
  A0h##S = *(const f16x8*)(hp0 + o_); A0l##S = *(const f16x8*)(hp0 + o_ + 512); \
  A1h##S = *(const f16x8*)(hp1 + o_); A1l##S = *(const f16x8*)(hp1 + o_ + 512); \
  A2h##S = *(const f16x8*)(hp2 + o_); A2l##S = *(const f16x8*)(hp2 + o_ + 512); \
  A3h##S = *(const f16x8*)(hp3 + o_); A3l##S = *(const f16x8*)(hp3 + o_ + 512); }
#define COMPSET(S) { \
  c10 = MFMA(A0h##S, Bh##S, c10); c20 = MFMA(A0l##S, Bh##S, c20); c20 = MFMA(A0h##S, Bl##S, c20); \
  c11 = MFMA(A1h##S, Bh##S, c11); c21 = MFMA(A1l##S, Bh##S, c21); c21 = MFMA(A1h##S, Bl##S, c21); \
  c12 = MFMA(A2h##S, Bh##S, c12); c22 = MFMA(A2l##S, Bh##S, c22); c22 = MFMA(A2h##S, Bl##S, c22); \
  c13 = MFMA(A3h##S, Bh##S, c13); c23 = MFMA(A3l##S, Bh##S, c23); c23 = MFMA(A3h##S, Bl##S, c23); }

  LOADSET(0, 0)
  for (int s=0; s<16; s+=2){
    LOADSET(1, s+1)
    COMPSET(0)
    if (s+2<16) LOADSET(0, s+2)
    COMPSET(1)
  }

  const float inv = 1.0f/4096.0f;
  int lm = lane & 15;
  int rb = (lane>>4)*4;
  size_t rbase = (size_t)blockIdx.y*R_N;
#define STT(mt, A1, A2) { \
  _Pragma("unroll") for (int rg=0; rg<4; ++rg){ \
    plog[(rbase + (mt)*16 + rb + rg)*(size_t)V_N + vb + lm] = A1[rg] + A2[rg]*inv; } }
  STT(0, c10, c20) STT(1, c11, c21) STT(2, c12, c22) STT(3, c13, c23)
}

__global__ __launch_bounds__(256) void k_stats(
    const float* __restrict__ plog, const float* __restrict__ b_out,
    float* __restrict__ pm, float* __restrict__ pz,
    float* __restrict__ pv, int* __restrict__ pi){
  int tid = threadIdx.x;
  int cx = tid & 15, ry = tid >> 4;
  int cb = blockIdx.x * 64;
  float4 bias = *(const float4*)&b_out[cb + cx*4];
  #pragma unroll
  for (int rr=0;rr<4;++rr){
    int row = ry*4 + rr;
    float4 a = *(const float4*)&plog[(size_t)row*V_N + cb + cx*4];
    float4 b2 = *(const float4*)&plog[(size_t)(R_N+row)*V_N + cb + cx*4];
    float v0 = a.x+b2.x+bias.x, v1 = a.y+b2.y+bias.y;
    float v2 = a.z+b2.z+bias.z, v3 = a.w+b2.w+bias.w;
    int   c0i = cb + cx*4;
    float tv0=-INFINITY,tv1=-INFINITY,tv2=-INFINITY,tv3=-INFINITY;
    int   ti0=0x7fffffff,ti1=0x7fffffff,ti2=0x7fffffff,ti3=0x7fffffff;
    ins4(v0,c0i+0,tv0,tv1,tv2,tv3,ti0,ti1,ti2,ti3);
    ins4(v1,c0i+1,tv0,tv1,tv2,tv3,ti0,ti1,ti2,ti3);
    ins4(v2,c0i+2,tv0,tv1,tv2,tv3,ti0,ti1,ti2,ti3);
    ins4(v3,c0i+3,tv0,tv1,tv2,tv3,ti0,ti1,ti2,ti3);
    float z = expf(v0-tv0)+expf(v1-tv0)+expf(v2-tv0)+expf(v3-tv0);
    #pragma unroll
    for (int msk=1; msk<16; msk<<=1){
      float om  = __shfl_xor(tv0, msk, 16);
      float oz  = __shfl_xor(z,   msk, 16);
      float ov1 = __shfl_xor(tv1, msk, 16);
      float ov2 = __shfl_xor(tv2, msk, 16);
      float ov3 = __shfl_xor(tv3, msk, 16);
      int   oi0 = __shfl_xor(ti0, msk, 16);
      int   oi1 = __shfl_xor(ti1, msk, 16);
      int   oi2 = __shfl_xor(ti2, msk, 16);
      int   oi3 = __shfl_xor(ti3, msk, 16);
      float M = fmaxf(tv0, om);
      z = z*expf(tv0-M) + oz*expf(om-M);
      ins4(om, oi0, tv0,tv1,tv2,tv3, ti0,ti1,ti2,ti3);
      ins4(ov1,oi1, tv0,tv1,tv2,tv3, ti0,ti1,ti2,ti3);
      ins4(ov2,oi2, tv0,tv1,tv2,tv3, ti0,ti1,ti2,ti3);
      ins4(ov3,oi3, tv0,tv1,tv2,tv3, ti0,ti1,ti2,ti3);
    }
    if (cx == 0){
      size_t base = (size_t)row*NB + blockIdx.x;
      pm[base]=tv0; pz[base]=z;
      pv[base*4+0]=tv0; pv[base*4+1]=tv1; pv[base*4+2]=tv2; pv[base*4+3]=tv3;
      pi[base*4+0]=ti0; pi[base*4+1]=ti1; pi[base*4+2]=ti2; pi[base*4+3]=ti3;
    }
  }
}

__global__ __launch_bounds__(256) void k_logits_fused(
    const float* __restrict__ h2t, const float* __restrict__ w_out,
    const float* __restrict__ b_out,
    float* __restrict__ pm, float* __restrict__ pz,
    float* __restrict__ pv, int* __restrict__ pi){
  int tid = threadIdx.x;
  int cx  = tid & 15, ry = tid >> 4;
  int cb  = blockIdx.x * 64;
  int sdd = tid >> 4, seg = tid & 15;
  __shared__ float Wt[32][64];
  __shared__ float Ht[32][64];
  float acc[4][4];
  #pragma unroll
  for (int cc=0;cc<4;++cc)
    #pragma unroll
    for (int rr=0;rr<4;++rr) acc[cc][rr]=0.f;
  const float* gW = w_out + (size_t)sdd*V_N + cb + seg*4;
  const float* gH = h2t + sdd*64 + seg*4;
#define FLQ(WA,WB,HA,HB, ch) { \
  const float* gWn = gW + (size_t)(ch)*32*V_N; \
  const float* gHn = gH + (size_t)(ch)*32*64; \
  WA = *(const float4*)gWn; WB = *(const float4*)(gWn + (size_t)16*V_N); \
  HA = *(const float4*)gHn; HB = *(const float4*)(gHn + 16*64); }
#define FSQ(WA,WB,HA,HB) { \
  *(float4*)&Wt[sdd][seg*4]    = WA; \
  *(float4*)&Wt[sdd+16][seg*4] = WB; \
  *(float4*)&Ht[sdd][seg*4]    = HA; \
  *(float4*)&Ht[sdd+16][seg*4] = HB; }
#define FCQ() { _Pragma("unroll 8") for (int dd=0; dd<32; ++dd){ \
    float4 w4 = *(const float4*)&Wt[dd][cx*4]; \
    float4 h4 = *(const float4*)&Ht[dd][ry*4]; \
    FMA16(w4, h4) } }
  float4 wA0,wB0,hA0,hB0, wA1,wB1,hA1,hB1;
  FLQ(wA0,wB0,hA0,hB0, 0)
  FSQ(wA0,wB0,hA0,hB0)
  FLQ(wA1,wB1,hA1,hB1, 1)
  __syncthreads();
  for (int ch=0; ch<32; ch+=2){
    if (ch+2<32) FLQ(wA0,wB0,hA0,hB0, ch+2)
    FCQ()
    __syncthreads();
    FSQ(wA1,wB1,hA1,hB1)
    __syncthreads();
    if (ch+3<32) FLQ(wA1,wB1,hA1,hB1, ch+3)
    FCQ()
    if (ch+2<32){
      __syncthreads();
      FSQ(wA0,wB0,hA0,hB0)
      __syncthreads();
    }
  }
  float4 bias = *(const float4*)&b_out[cb + cx*4];
  #pragma unroll
  for (int rr=0;rr<4;++rr){
    float v0 = acc[0][rr]+bias.x, v1 = acc[1][rr]+bias.y;
    float v2 = acc[2][rr]+bias.z, v3 = acc[3][rr]+bias.w;
    int   c0i = cb + cx*4;
    float tv0=-INFINITY,tv1=-INFINITY,tv2=-INFINITY,tv3=-INFINITY;
    int   ti0=0x7fffffff,ti1=0x7fffffff,ti2=0x7fffffff,ti3=0x7fffffff;
    ins4(v0,c0i+0,tv0,tv1,tv2,tv3,ti0,ti1,ti2,ti3);
    ins4(v1,c0i+1,tv0,tv1,tv2,tv3,ti0,ti1,ti2,ti3);
    ins4(v2,c0i+2,tv0,tv1,tv2,tv3,ti0,ti1,ti2,ti3);
    ins4(v3,c0i+3,tv0,tv1,tv2,tv3,ti0,ti1,ti2,ti3);
    float z = expf(v0-tv0)+expf(v1-tv0)+expf(v2-tv0)+expf(v3-tv0);
    #pragma unroll
    for (int msk=1; msk<16; msk<<=1){
      float om  = __shfl_xor(tv0, msk, 16);
      float oz  = __shfl_xor(z,   msk, 16);
      float ov1 = __shfl_xor(tv1, msk, 16);
      float ov2 = __shfl_xor(tv2, msk, 16);
      float ov3 = __shfl_xor(tv3, msk, 16);
      int   oi0 = __shfl_xor(ti0, msk, 16);
      int   oi1 = __shfl_xor(ti1, msk, 16);
      int   oi2 = __shfl_xor(ti2, msk, 16);
      int   oi3 = __shfl_xor(ti3, msk, 16);
      float M = fmaxf(tv0, om);
      z = z*expf(tv0-M) + oz*expf(om-M);
      ins4(om, oi0, tv0,tv1,tv2,tv3, ti0,ti1,ti2,ti3);
      ins4(ov1,oi1, tv0,tv1,tv2,tv3, ti0,ti1,ti2,ti3);
      ins4(ov2,oi2, tv0,tv1,tv2,tv3, ti0,ti1,ti2,ti3);
      ins4(ov3,oi3, tv0,tv1,tv2,tv3, ti0,ti1,ti2,ti3);
    }
    if (cx == 0){
      int row = ry*4 + rr;
      size_t base = (size_t)row*NB + blockIdx.x;
      pm[base]=tv0; pz[base]=z;
      pv[base*4+0]=tv0; pv[base*4+1]=tv1; pv[base*4+2]=tv2; pv[base*4+3]=tv3;
      pi[base*4+0]=ti0; pi[base*4+1]=ti1; pi[base*4+2]=ti2; pi[base*4+3]=ti3;
    }
  }
}

__global__ __launch_bounds__(256) void k_final(
    const float* __restrict__ pm, const float* __restrict__ pz,
    const float* __restrict__ pv, const int* __restrict__ pi,
    float* __restrict__ scores, int* __restrict__ out, int t,
    float* __restrict__ xn,
    const float* __restrict__ enc_inputs, const float* __restrict__ enc_outputs,
    const float* __restrict__ embed){
  int b = blockIdx.x, tid = threadIdx.x;
  int kk = tid >> 6, lane = tid & 63;
  __shared__ float fM[KBEAM], fZ[KBEAM], fV[16];
  __shared__ int   fI[16], sw[KBEAM];
  int nk = (t==0) ? 1 : KBEAM;
  if (kk < nk){
    size_t rb = (size_t)(kk*B_N + b)*NB;
    float m=-INFINITY, z=0.f;
    float av0=-INFINITY,av1=-INFINITY,av2=-INFINITY,av3=-INFINITY;
    int   ai0=0x7fffffff,ai1=0x7fffffff,ai2=0x7fffffff,ai3=0x7fffffff;
    for (int p0=lane; p0<NB; p0+=64){
      size_t p = rb + p0;
      float mf = pm[p];
      float M = fmaxf(m, mf);
      z = z*expf(m-M) + pz[p]*expf(mf-M);
      m = M;
      #pragma unroll
      for (int q=0;q<4;++q)
        ins4(pv[p*4+q], pi[p*4+q], av0,av1,av2,av3, ai0,ai1,ai2,ai3);
    }
    #pragma unroll
    for (int msk=1; msk<64; msk<<=1){
      float om  = __shfl_xor(m,   msk);
      float oz  = __shfl_xor(z,   msk);
      float ov0 = __shfl_xor(av0, msk);
      float ov1 = __shfl_xor(av1, msk);
      float ov2 = __shfl_xor(av2, msk);
      float ov3 = __shfl_xor(av3, msk);
      int   oi0 = __shfl_xor(ai0, msk);
      int   oi1 = __shfl_xor(ai1, msk);
      int   oi2 = __shfl_xor(ai2, msk);
      int   oi3 = __shfl_xor(ai3, msk);
      float M = fmaxf(m, om);
      z = z*expf(m-M) + oz*expf(om-M);
      m = M;
      ins4(ov0,oi0, av0,av1,av2,av3, ai0,ai1,ai2,ai3);
      ins4(ov1,oi1, av0,av1,av2,av3, ai0,ai1,ai2,ai3);
      ins4(ov2,oi2, av0,av1,av2,av3, ai0,ai1,ai2,ai3);
      ins4(ov3,oi3, av0,av1,av2,av3, ai0,ai1,ai2,ai3);
    }
    if (lane == 0){
      fM[kk]=m; fZ[kk]=z;
      fV[kk*4+0]=av0; fV[kk*4+1]=av1; fV[kk*4+2]=av2; fV[kk*4+3]=av3;
      fI[kk*4+0]=ai0; fI[kk*4+1]=ai1; fI[kk*4+2]=ai2; fI[kk*4+3]=ai3;
    }
  }
  __syncthreads();
  if (tid==0){
    if (t==0){
      #pragma unroll
      for (int j=0;j<4;++j){
        float p = expf(fV[j]-fM[0])/fZ[0];
        scores[b*4+j] = p;
        out[j*(B_N*S_LEN) + b*S_LEN] = fI[j];
        sw[j] = fI[j];
      }
    } else {
      float cv[16]; int cj[16];
      for (int k=0;k<4;++k){
        float s = scores[b*4+k];
        #pragma unroll
        for (int j=0;j<4;++j){
          cv[k*4+j] = expf(fV[k*4+j]-fM[k])/fZ[k]*s;
          cj[k*4+j] = k*V_N + fI[k*4+j];
        }
      }
      bool used[16];
      for (int i=0;i<16;++i) used[i]=false;
      for (int rank=0;rank<4;++rank){
        int best=-1;
        for (int i=0;i<16;++i){
          if (used[i]) continue;
          if (best<0 || cv[i]>cv[best] || (cv[i]==cv[best] && cj[i]<cj[best])) best=i;
        }
        used[best]=true;
        out[rank*(B_N*S_LEN) + b*S_LEN + t] = cj[best];
        sw[rank] = cj[best] % V_N;
      }
    }
  }
  __syncthreads();
  if (t < S_LEN-1){
    const float* ein = enc_inputs  + (size_t)(t+1)*B_N*E_N + (size_t)b*E_N;
    const float* eo  = enc_outputs + (size_t)(t+1)*B_N*H_N + (size_t)b*H_N;
    #pragma unroll
    for (int j=0;j<KBEAM;++j){
      float* xr = xn + (size_t)(j*B_N + b)*D2;
      const float* em = embed + (size_t)sw[j]*E_N;
      xr[tid]       = em[tid];
      xr[E_N + tid] = ein[tid];
      #pragma unroll
      for (int q=0;q<4;++q) xr[2*E_N + q*256 + tid] = eo[q*256 + tid];
    }
  }
}

extern "C" void kernel_launch(void* const* d_in, const int* in_sizes, int n_in,
                              void* d_out, int out_size, void* d_ws, size_t ws_size,
                              hipStream_t stream) {
  (void)in_sizes; (void)n_in; (void)out_size;
  const float* enc_h_n     = (const float*)d_in[0];
  const float* enc_c_n     = (const float*)d_in[1];
  const float* enc_outputs = (const float*)d_in[2];
  const float* enc_inputs  = (const float*)d_in[3];
  const float* embed       = (const float*)d_in[4];
  const float* w_ih        = (const float*)d_in[5];
  const float* w_hh        = (const float*)d_in[6];
  const float* b_lstm      = (const float*)d_in[7];
  const float* w_out       = (const float*)d_in[8];
  const float* b_out       = (const float*)d_in[9];
  int* out = (int*)d_out;

  float* ws = (float*)d_ws;
  const size_t FRONTF = (size_t)R_N*D2*2 + (size_t)R_N*H_N + (size_t)H_N*R_N; // 458752
  const size_t HSPLF  = (size_t)R_N*H_N;        // packed fp16 pair (256 KB)
  const size_t PLOGF  = (size_t)LKS*R_N*V_N;    // 4,096,000
  const size_t GPARTF = (size_t)NDS*R_N*4096;   // 5,242,880
  const size_t STATF  = (size_t)R_N*NB*10;      // 320,000
  const size_t WSPLF  = (size_t)V_N*H_N;        // packed fp16 pair (128 MB)
  size_t bigF = (PLOGF > GPARTF ? PLOGF : GPARTF);
  size_t need_split = (FRONTF + HSPLF + bigF + STATF + 64 + WSPLF)*sizeof(float);
  bool use_split = (ws_size >= need_split);

  float* xA     = ws;
  float* xB     = xA + (size_t)R_N*D2;
  float* cbuf   = xB + (size_t)R_N*D2;
  float* h2t    = cbuf + (size_t)R_N*H_N;
  f16*   hpk    = (f16*)(h2t + (size_t)H_N*R_N);
  float* big    = h2t + (size_t)H_N*R_N + HSPLF;
  float* gpart  = big;
  float* plog   = big;
  float* pm     = big + bigF;
  float* pz     = pm + (size_t)R_N*NB;
  float* pv     = pz + (size_t)R_N*NB;
  int*   pi     = (int*)(pv + (size_t)R_N*NB*4);
  float* scoresb= (float*)(pi + (size_t)R_N*NB*4);
  f16*   wpk    = (f16*)(scoresb + 64);

  if (use_split){
    k_convw<<<dim3(V_N/64, H_N/64), 256, 0, stream>>>(w_out, wpk);
  }
  k_init<<<R_N, 256, 0, stream>>>(enc_h_n, enc_c_n, enc_outputs, enc_inputs, embed, xA, cbuf);

  for (int t=0; t<S_LEN; ++t){
    float* xc = (t & 1) ? xB : xA;
    float* xn = (t & 1) ? xA : xB;
    k_gates <<<dim3(64, NDS), 256, 0, stream>>>(xc, w_ih, w_hh, gpart);
    k_lstm  <<<dim3(R_N, 4), 256, 0, stream>>>(gpart, b_lstm, cbuf, xn, h2t, hpk);
    if (use_split){
      k_logits_mfma<<<dim3(V_N/64, LKS), 256, 0, stream>>>(wpk, hpk, plog);
      k_stats<<<NB, 256, 0, stream>>>(plog, b_out, pm, pz, pv, pi);
    } else {
      k_logits_fused<<<NB, 256, 0, stream>>>(h2t, w_out, b_out, pm, pz, pv, pi);
    }
    k_final <<<B_N, 256, 0, stream>>>(pm, pz, pv, pi, scoresb, out, t, xn,
                                      enc_inputs, enc_outputs, embed);
  }
}

// Round 20
// 2852.341 us; speedup vs baseline: 1.5508x; 1.0900x over previous
//
#include <hip/hip_runtime.h>
#include <math.h>

#define S_LEN 32
#define B_N   16
#define H_N   1024
#define E_N   256
#define V_N   32000
#define KBEAM 4
#define DIN   1536
#define D2    2560   // DIN + H_N
#define R_N   64     // KBEAM * B_N rows of state
#define NDS   20     // K-slices for gates GEMM (128 each, 4 chunks)
#define NB    500    // stats/final col-blocks = V_N/64

typedef _Float16 f16;
typedef f16   f16x8 __attribute__((ext_vector_type(8)));
typedef float f32x4 __attribute__((ext_vector_type(4)));
#define MFMA(A,B,C) __builtin_amdgcn_mfma_f32_16x16x32_f16(A,B,C,0,0,0)

__device__ __forceinline__ float sigmf(float x){ return 1.0f/(1.0f+expf(-x)); }
__device__ __forceinline__ bool better(float v1,int i1,float v2,int i2){
  return (v1>v2) || (v1==v2 && i1<i2);
}
__device__ __forceinline__ void ins4(float bv,int bi,
    float&av0,float&av1,float&av2,float&av3,int&ai0,int&ai1,int&ai2,int&ai3){
  if (better(bv,bi,av3,ai3)){ av3=bv; ai3=bi;
    if (better(av3,ai3,av2,ai2)){ float t=av2;av2=av3;av3=t; int q=ai2;ai2=ai3;ai3=q;
      if (better(av2,ai2,av1,ai1)){ t=av1;av1=av2;av2=t; q=ai1;ai1=ai2;ai2=q;
        if (better(av1,ai1,av0,ai0)){ t=av0;av0=av1;av1=t; q=ai0;ai0=ai1;ai1=q; } } } }
}

#define FMA16(w4, h4) { \
  acc[0][0]=fmaf(w4.x,h4.x,acc[0][0]); acc[0][1]=fmaf(w4.x,h4.y,acc[0][1]); \
  acc[0][2]=fmaf(w4.x,h4.z,acc[0][2]); acc[0][3]=fmaf(w4.x,h4.w,acc[0][3]); \
  acc[1][0]=fmaf(w4.y,h4.x,acc[1][0]); acc[1][1]=fmaf(w4.y,h4.y,acc[1][1]); \
  acc[1][2]=fmaf(w4.y,h4.z,acc[1][2]); acc[1][3]=fmaf(w4.y,h4.w,acc[1][3]); \
  acc[2][0]=fmaf(w4.z,h4.x,acc[2][0]); acc[2][1]=fmaf(w4.z,h4.y,acc[2][1]); \
  acc[2][2]=fmaf(w4.z,h4.z,acc[2][2]); acc[2][3]=fmaf(w4.z,h4.w,acc[2][3]); \
  acc[3][0]=fmaf(w4.w,h4.x,acc[3][0]); acc[3][1]=fmaf(w4.w,h4.y,acc[3][1]); \
  acc[3][2]=fmaf(w4.w,h4.z,acc[3][2]); acc[3][3]=fmaf(w4.w,h4.w,acc[3][3]); }

__global__ __launch_bounds__(256) void k_init(
    const float* __restrict__ enc_h_n, const float* __restrict__ enc_c_n,
    const float* __restrict__ enc_outputs, const float* __restrict__ enc_inputs,
    const float* __restrict__ embed, float* __restrict__ x, float* __restrict__ c){
  int r = blockIdx.x, tid = threadIdx.x, b = r & 15;
  float* xr = x + (size_t)r*D2;
  xr[tid]        = embed[E_N + tid];
  xr[E_N + tid]  = enc_inputs[b*E_N + tid];
  #pragma unroll
  for (int q=0;q<4;++q) xr[2*E_N + q*256 + tid] = enc_outputs[b*H_N + q*256 + tid];
  #pragma unroll
  for (int q=0;q<4;++q) xr[DIN + q*256 + tid]   = enc_h_n[b*H_N + q*256 + tid];
  #pragma unroll
  for (int q=0;q<4;++q) c[(size_t)r*H_N + q*256 + tid] = enc_c_n[b*H_N + q*256 + tid];
}

// ---- one-time: transpose + fp16-split + fragment-pack w_out -> wpk.
__global__ __launch_bounds__(256) void k_convw(
    const float* __restrict__ w, f16* __restrict__ wpk){
  __shared__ f16 Th[64][66];
  __shared__ f16 Tl[64][66];
  int v0 = blockIdx.x*64, d0 = blockIdx.y*64;
  int tid = threadIdx.x;
  int r = tid >> 4, cq = (tid & 15)*4;
  #pragma unroll
  for (int rr=0; rr<4; ++rr){
    int d = r + rr*16;
    float4 x = *(const float4*)&w[(size_t)(d0+d)*V_N + v0 + cq];
    f16 h;
    h=(f16)x.x; Th[d][cq+0]=h; Tl[d][cq+0]=(f16)((x.x-(float)h)*4096.0f);
    h=(f16)x.y; Th[d][cq+1]=h; Tl[d][cq+1]=(f16)((x.y-(float)h)*4096.0f);
    h=(f16)x.z; Th[d][cq+2]=h; Tl[d][cq+2]=(f16)((x.z-(float)h)*4096.0f);
    h=(f16)x.w; Th[d][cq+3]=h; Tl[d][cq+3]=(f16)((x.w-(float)h)*4096.0f);
  }
  __syncthreads();
  int T2 = tid >> 6, l = tid & 63;
  int lm = l & 15, kq = l >> 4;
  int Tg = blockIdx.x*4 + T2;
  #pragma unroll
  for (int ks2=0; ks2<2; ++ks2){
    int ksg = blockIdx.y*2 + ks2;
    f16x8 a, b2;
    #pragma unroll
    for (int i=0;i<8;++i){
      int dd = ks2*32 + kq*8 + i;
      a[i]  = Th[dd][T2*16 + lm];
      b2[i] = Tl[dd][T2*16 + lm];
    }
    size_t base = ((size_t)(Tg*32 + ksg)*2)*512 + l*8;
    *(f16x8*)&wpk[base]       = a;
    *(f16x8*)&wpk[base + 512] = b2;
  }
}

#define GWLD(d, off) (*(const float4*)((((d) < DIN) ? (w_ih + (size_t)(d)*4096) \
                       : (w_hh + (size_t)((d)-DIN)*4096)) + (off)))
__global__ __launch_bounds__(256) void k_gates(
    const float* __restrict__ x, const float* __restrict__ w_ih,
    const float* __restrict__ w_hh, float* __restrict__ gpart){
  int tid = threadIdx.x;
  int jt = blockIdx.x, ks = blockIdx.y;
  int cx = tid & 15, ry = tid >> 4;
  int cb = jt*64;
  int wdd = tid >> 4, wseg = tid & 15;
  int xrow = tid >> 3, xseg = tid & 7;

  __shared__ float Wt0[32][64], Wt1[32][64];
  __shared__ float Xt0[32][68], Xt1[32][68];

  float acc[4][4];
  #pragma unroll
  for (int cc=0;cc<4;++cc)
    #pragma unroll
    for (int rr=0;rr<4;++rr) acc[cc][rr]=0.f;

  int d0 = ks*128;
  const float* xp0 = x + (size_t)xrow*D2 + d0 + xseg*4;
  const float* xp1 = x + (size_t)(xrow+32)*D2 + d0 + xseg*4;

#define GLQ(WA,WB,X0,X1, ch) { int d_ = d0 + (ch)*32; \
  WA = GWLD(d_+wdd,    cb+wseg*4); \
  WB = GWLD(d_+16+wdd, cb+wseg*4); \
  X0 = *(const float4*)(xp0 + (ch)*32); \
  X1 = *(const float4*)(xp1 + (ch)*32); }
#define GSQ(Wt,Xt, WA,WB,X0,X1) { \
  *(float4*)&Wt[wdd][wseg*4]    = WA; \
  *(float4*)&Wt[wdd+16][wseg*4] = WB; \
  Xt[xseg*4+0][xrow] = X0.x; Xt[xseg*4+1][xrow] = X0.y; \
  Xt[xseg*4+2][xrow] = X0.z; Xt[xseg*4+3][xrow] = X0.w; \
  Xt[xseg*4+0][xrow+32] = X1.x; Xt[xseg*4+1][xrow+32] = X1.y; \
  Xt[xseg*4+2][xrow+32] = X1.z; Xt[xseg*4+3][xrow+32] = X1.w; }
#define GCQ(Wt,Xt) { _Pragma("unroll 8") for (int dd=0; dd<32; ++dd){ \
    float4 w4 = *(const float4*)&Wt[dd][cx*4]; \
    float4 h4 = *(const float4*)&Xt[dd][ry*4]; \
    FMA16(w4, h4) } }

  float4 wA0,wB0,x00,x10, wA1,wB1,x01,x11;
  GLQ(wA0,wB0,x00,x10, 0)
  GSQ(Wt0,Xt0, wA0,wB0,x00,x10)
  GLQ(wA1,wB1,x01,x11, 1)
  __syncthreads();

  for (int ch=0; ch<4; ch+=2){
    if (ch+2<4) GLQ(wA0,wB0,x00,x10, ch+2)
    GSQ(Wt1,Xt1, wA1,wB1,x01,x11)
    GCQ(Wt0,Xt0)
    __syncthreads();
    if (ch+3<4) GLQ(wA1,wB1,x01,x11, ch+3)
    if (ch+2<4) GSQ(Wt0,Xt0, wA0,wB0,x00,x10)
    GCQ(Wt1,Xt1)
    if (ch+2<4) __syncthreads();
  }
  #pragma unroll
  for (int rr=0;rr<4;++rr){
    float4 o; o.x=acc[0][rr]; o.y=acc[1][rr]; o.z=acc[2][rr]; o.w=acc[3][rr];
    *(float4*)&gpart[((size_t)(ks*R_N + ry*4+rr))*4096 + cb + cx*4] = o;
  }
}

__global__ __launch_bounds__(256) void k_lstm(
    const float* __restrict__ gpart, const float* __restrict__ b_lstm,
    float* __restrict__ c, float* __restrict__ xn, float* __restrict__ h2t,
    f16* __restrict__ hpk){
  int r = blockIdx.x, tid = threadIdx.x;
  int j = blockIdx.y*256 + tid;
  float gi = b_lstm[j], gf = b_lstm[1024+j], gg = b_lstm[2048+j], go = b_lstm[3072+j];
  #pragma unroll
  for (int ds=0; ds<NDS; ++ds){
    size_t base = ((size_t)ds*R_N + r)*4096;
    gi += gpart[base + j];      gf += gpart[base + 1024 + j];
    gg += gpart[base + 2048+j]; go += gpart[base + 3072 + j];
  }
  float cv = c[(size_t)r*H_N + j];
  float c2 = sigmf(gf)*cv + sigmf(gi)*tanhf(gg);
  float h2 = sigmf(go)*tanhf(c2);
  c[(size_t)r*H_N + j] = c2;
  xn[(size_t)r*D2 + DIN + j] = h2;
  h2t[(size_t)j*R_N + r] = h2;
  f16 hh = (f16)h2;
  int m = r >> 4, lm = r & 15;
  int ks = j >> 5, kq = (j & 31) >> 3, i = j & 7;
  int l = lm + 16*kq;
  size_t base2 = ((size_t)(m*32 + ks)*2)*512 + l*8 + i;
  hpk[base2]       = hh;
  hpk[base2 + 512] = (f16)((h2 - (float)hh)*4096.0f);
}

// ---- logits via MFMA fp16-split (K=1024, no split) + fused in-LDS stats.
// grid 500 x 256 thr (4 waves; wave = 16 vocab x 64 rows). All loads 1KB
// coalesced, depth-2 prefetch. After MFMA: bias+combine -> LDS [64][68],
// barrier, then per-row softmax stats & top-4 (k_stats logic) from LDS.
__global__ __launch_bounds__(256) void k_logits_mfma(
    const f16* __restrict__ wpk, const f16* __restrict__ hpk,
    const float* __restrict__ b_out,
    float* __restrict__ pm, float* __restrict__ pz,
    float* __restrict__ pv, int* __restrict__ pi){
  int tid = threadIdx.x;
  int lane = tid & 63;
  int wv = tid >> 6;
  int T  = blockIdx.x*4 + wv;
  int vb = T*16;

  const f16* wp  = wpk + ((size_t)(T*32))*2*512 + lane*8;
  const f16* hp0 = hpk + ((size_t)(0*32))*2*512 + lane*8;
  const f16* hp1 = hpk + ((size_t)(1*32))*2*512 + lane*8;
  const f16* hp2 = hpk + ((size_t)(2*32))*2*512 + lane*8;
  const f16* hp3 = hpk + ((size_t)(3*32))*2*512 + lane*8;

  f32x4 c10={0,0,0,0}, c11={0,0,0,0}, c12={0,0,0,0}, c13={0,0,0,0};
  f32x4 c20={0,0,0,0}, c21={0,0,0,0}, c22={0,0,0,0}, c23={0,0,0,0};

  f16x8 Bh0,Bl0,A0h0,A1h0,A2h0,A3h0,A0l0,A1l0,A2l0,A3l0;
  f16x8 Bh1,Bl1,A0h1,A1h1,A2h1,A3h1,A0l1,A1l1,A2l1,A3l1;

#define LOADSET(S, s) { size_t o_ = (size_t)(s)*1024; \
  Bh##S  = *(const f16x8*)(wp + o_);  Bl##S  = *(const f16x8*)(wp + o_ + 512); \
  A0h##S = *(const f16x8*)(hp0 + o_); A0l##S = *(const f16x8*)(hp0 + o_ + 512); \
  A1h##S = *(const f16x8*)(hp1 + o_); A1l##S = *(const f16x8*)(hp1 + o_ + 512); \
  A2h##S = *(const f16x8*)(hp2 + o_); A2l##S = *(const f16x8*)(hp2 + o_ + 512); \
  A3h##S = *(const f16x8*)(hp3 + o_); A3l##S = *(const f16x8*)(hp3 + o_ + 512); }
#define COMPSET(S) { \
  c10 = MFMA(A0h##S, Bh##S, c10); c20 = MFMA(A0l##S, Bh##S, c20); c20 = MFMA(A0h##S, Bl##S, c20); \
  c11 = MFMA(A1h##S, Bh##S, c11); c21 = MFMA(A1l##S, Bh##S, c21); c21 = MFMA(A1h##S, Bl##S, c21); \
  c12 = MFMA(A2h##S, Bh##S, c12); c22 = MFMA(A2l##S, Bh##S, c22); c22 = MFMA(A2h##S, Bl##S, c22); \
  c13 = MFMA(A3h##S, Bh##S, c13); c23 = MFMA(A3l##S, Bh##S, c23); c23 = MFMA(A3h##S, Bl##S, c23); }

  LOADSET(0, 0)
  for (int s=0; s<32; s+=2){
    LOADSET(1, s+1)
    COMPSET(0)
    if (s+2<32) LOADSET(0, s+2)
    COMPSET(1)
  }

  __shared__ float Ls[64][68];

  const float inv = 1.0f/4096.0f;
  int lm = lane & 15;
  int rb = (lane>>4)*4;
  float bias = b_out[vb + lm];
#define STT(mt, A1, A2) { \
  _Pragma("unroll") for (int rg=0; rg<4; ++rg){ \
    Ls[(mt)*16 + rb + rg][wv*16 + lm] = A1[rg] + A2[rg]*inv + bias; } }
  STT(0, c10, c20) STT(1, c11, c21) STT(2, c12, c22) STT(3, c13, c23)
  __syncthreads();

  // stats phase: per-row (64 cols) max, sumexp, top-4; width-16 butterfly.
  int cx = tid & 15, ry = tid >> 4;
  int cb = blockIdx.x * 64;
  #pragma unroll
  for (int rr=0;rr<4;++rr){
    int row = ry*4 + rr;
    float v0 = Ls[row][cx*4+0], v1 = Ls[row][cx*4+1];
    float v2 = Ls[row][cx*4+2], v3 = Ls[row][cx*4+3];
    int   c0i = cb + cx*4;
    float tv0=-INFINITY,tv1=-INFINITY,tv2=-INFINITY,tv3=-INFINITY;
    int   ti0=0x7fffffff,ti1=0x7fffffff,ti2=0x7fffffff,ti3=0x7fffffff;
    ins4(v0,c0i+0,tv0,tv1,tv2,tv3,ti0,ti1,ti2,ti3);
    ins4(v1,c0i+1,tv0,tv1,tv2,tv3,ti0,ti1,ti2,ti3);
    ins4(v2,c0i+2,tv0,tv1,tv2,tv3,ti0,ti1,ti2,ti3);
    ins4(v3,c0i+3,tv0,tv1,tv2,tv3,ti0,ti1,ti2,ti3);
    float z = expf(v0-tv0)+expf(v1-tv0)+expf(v2-tv0)+expf(v3-tv0);
    #pragma unroll
    for (int msk=1; msk<16; msk<<=1){
      float om  = __shfl_xor(tv0, msk, 16);
      float oz  = __shfl_xor(z,   msk, 16);
      float ov1 = __shfl_xor(tv1, msk, 16);
      float ov2 = __shfl_xor(tv2, msk, 16);
      float ov3 = __shfl_xor(tv3, msk, 16);
      int   oi0 = __shfl_xor(ti0, msk, 16);
      int   oi1 = __shfl_xor(ti1, msk, 16);
      int   oi2 = __shfl_xor(ti2, msk, 16);
      int   oi3 = __shfl_xor(ti3, msk, 16);
      float M = fmaxf(tv0, om);
      z = z*expf(tv0-M) + oz*expf(om-M);
      ins4(om, oi0, tv0,tv1,tv2,tv3, ti0,ti1,ti2,ti3);
      ins4(ov1,oi1, tv0,tv1,tv2,tv3, ti0,ti1,ti2,ti3);
      ins4(ov2,oi2, tv0,tv1,tv2,tv3, ti0,ti1,ti2,ti3);
      ins4(ov3,oi3, tv0,tv1,tv2,tv3, ti0,ti1,ti2,ti3);
    }
    if (cx == 0){
      size_t base = (size_t)row*NB + blockIdx.x;
      pm[base]=tv0; pz[base]=z;
      pv[base*4+0]=tv0; pv[base*4+1]=tv1; pv[base*4+2]=tv2; pv[base*4+3]=tv3;
      pi[base*4+0]=ti0; pi[base*4+1]=ti1; pi[base*4+2]=ti2; pi[base*4+3]=ti3;
    }
  }
}

// ---- fallback: fused fp32 logits+stats (round-6 kernel), if ws too small.
__global__ __launch_bounds__(256) void k_logits_fused(
    const float* __restrict__ h2t, const float* __restrict__ w_out,
    const float* __restrict__ b_out,
    float* __restrict__ pm, float* __restrict__ pz,
    float* __restrict__ pv, int* __restrict__ pi){
  int tid = threadIdx.x;
  int cx  = tid & 15, ry = tid >> 4;
  int cb  = blockIdx.x * 64;
  int sdd = tid >> 4, seg = tid & 15;
  __shared__ float Wt[32][64];
  __shared__ float Ht[32][64];
  float acc[4][4];
  #pragma unroll
  for (int cc=0;cc<4;++cc)
    #pragma unroll
    for (int rr=0;rr<4;++rr) acc[cc][rr]=0.f;
  const float* gW = w_out + (size_t)sdd*V_N + cb + seg*4;
  const float* gH = h2t + sdd*64 + seg*4;
#define FLQ(WA,WB,HA,HB, ch) { \
  const float* gWn = gW + (size_t)(ch)*32*V_N; \
  const float* gHn = gH + (size_t)(ch)*32*64; \
  WA = *(const float4*)gWn; WB = *(const float4*)(gWn + (size_t)16*V_N); \
  HA = *(const float4*)gHn; HB = *(const float4*)(gHn + 16*64); }
#define FSQ(WA,WB,HA,HB) { \
  *(float4*)&Wt[sdd][seg*4]    = WA; \
  *(float4*)&Wt[sdd+16][seg*4] = WB; \
  *(float4*)&Ht[sdd][seg*4]    = HA; \
  *(float4*)&Ht[sdd+16][seg*4] = HB; }
#define FCQ() { _Pragma("unroll 8") for (int dd=0; dd<32; ++dd){ \
    float4 w4 = *(const float4*)&Wt[dd][cx*4]; \
    float4 h4 = *(const float4*)&Ht[dd][ry*4]; \
    FMA16(w4, h4) } }
  float4 wA0,wB0,hA0,hB0, wA1,wB1,hA1,hB1;
  FLQ(wA0,wB0,hA0,hB0, 0)
  FSQ(wA0,wB0,hA0,hB0)
  FLQ(wA1,wB1,hA1,hB1, 1)
  __syncthreads();
  for (int ch=0; ch<32; ch+=2){
    if (ch+2<32) FLQ(wA0,wB0,hA0,hB0, ch+2)
    FCQ()
    __syncthreads();
    FSQ(wA1,wB1,hA1,hB1)
    __syncthreads();
    if (ch+3<32) FLQ(wA1,wB1,hA1,hB1, ch+3)
    FCQ()
    if (ch+2<32){
      __syncthreads();
      FSQ(wA0,wB0,hA0,hB0)
      __syncthreads();
    }
  }
  float4 bias = *(const float4*)&b_out[cb + cx*4];
  #pragma unroll
  for (int rr=0;rr<4;++rr){
    float v0 = acc[0][rr]+bias.x, v1 = acc[1][rr]+bias.y;
    float v2 = acc[2][rr]+bias.z, v3 = acc[3][rr]+bias.w;
    int   c0i = cb + cx*4;
    float tv0=-INFINITY,tv1=-INFINITY,tv2=-INFINITY,tv3=-INFINITY;
    int   ti0=0x7fffffff,ti1=0x7fffffff,ti2=0x7fffffff,ti3=0x7fffffff;
    ins4(v0,c0i+0,tv0,tv1,tv2,tv3,ti0,ti1,ti2,ti3);
    ins4(v1,c0i+1,tv0,tv1,tv2,tv3,ti0,ti1,ti2,ti3);
    ins4(v2,c0i+2,tv0,tv1,tv2,tv3,ti0,ti1,ti2,ti3);
    ins4(v3,c0i+3,tv0,tv1,tv2,tv3,ti0,ti1,ti2,ti3);
    float z = expf(v0-tv0)+expf(v1-tv0)+expf(v2-tv0)+expf(v3-tv0);
    #pragma unroll
    for (int msk=1; msk<16; msk<<=1){
      float om  = __shfl_xor(tv0, msk, 16);
      float oz  = __shfl_xor(z,   msk, 16);
      float ov1 = __shfl_xor(tv1, msk, 16);
      float ov2 = __shfl_xor(tv2, msk, 16);
      float ov3 = __shfl_xor(tv3, msk, 16);
      int   oi0 = __shfl_xor(ti0, msk, 16);
      int   oi1 = __shfl_xor(ti1, msk, 16);
      int   oi2 = __shfl_xor(ti2, msk, 16);
      int   oi3 = __shfl_xor(ti3, msk, 16);
      float M = fmaxf(tv0, om);
      z = z*expf(tv0-M) + oz*expf(om-M);
      ins4(om, oi0, tv0,tv1,tv2,tv3, ti0,ti1,ti2,ti3);
      ins4(ov1,oi1, tv0,tv1,tv2,tv3, ti0,ti1,ti2,ti3);
      ins4(ov2,oi2, tv0,tv1,tv2,tv3, ti0,ti1,ti2,ti3);
      ins4(ov3,oi3, tv0,tv1,tv2,tv3, ti0,ti1,ti2,ti3);
    }
    if (cx == 0){
      int row = ry*4 + rr;
      size_t base = (size_t)row*NB + blockIdx.x;
      pm[base]=tv0; pz[base]=z;
      pv[base*4+0]=tv0; pv[base*4+1]=tv1; pv[base*4+2]=tv2; pv[base*4+3]=tv3;
      pi[base*4+0]=ti0; pi[base*4+1]=ti1; pi[base*4+2]=ti2; pi[base*4+3]=ti3;
    }
  }
}

__global__ __launch_bounds__(256) void k_final(
    const float* __restrict__ pm, const float* __restrict__ pz,
    const float* __restrict__ pv, const int* __restrict__ pi,
    float* __restrict__ scores, int* __restrict__ out, int t,
    float* __restrict__ xn,
    const float* __restrict__ enc_inputs, const float* __restrict__ enc_outputs,
    const float* __restrict__ embed){
  int b = blockIdx.x, tid = threadIdx.x;
  int kk = tid >> 6, lane = tid & 63;
  __shared__ float fM[KBEAM], fZ[KBEAM], fV[16];
  __shared__ int   fI[16], sw[KBEAM];
  int nk = (t==0) ? 1 : KBEAM;
  if (kk < nk){
    size_t rb = (size_t)(kk*B_N + b)*NB;
    float m=-INFINITY, z=0.f;
    float av0=-INFINITY,av1=-INFINITY,av2=-INFINITY,av3=-INFINITY;
    int   ai0=0x7fffffff,ai1=0x7fffffff,ai2=0x7fffffff,ai3=0x7fffffff;
    for (int p0=lane; p0<NB; p0+=64){
      size_t p = rb + p0;
      float mf = pm[p];
      float M = fmaxf(m, mf);
      z = z*expf(m-M) + pz[p]*expf(mf-M);
      m = M;
      #pragma unroll
      for (int q=0;q<4;++q)
        ins4(pv[p*4+q], pi[p*4+q], av0,av1,av2,av3, ai0,ai1,ai2,ai3);
    }
    #pragma unroll
    for (int msk=1; msk<64; msk<<=1){
      float om  = __shfl_xor(m,   msk);
      float oz  = __shfl_xor(z,   msk);
      float ov0 = __shfl_xor(av0, msk);
      float ov1 = __shfl_xor(av1, msk);
      float ov2 = __shfl_xor(av2, msk);
      float ov3 = __shfl_xor(av3, msk);
      int   oi0 = __shfl_xor(ai0, msk);
      int   oi1 = __shfl_xor(ai1, msk);
      int   oi2 = __shfl_xor(ai2, msk);
      int   oi3 = __shfl_xor(ai3, msk);
      float M = fmaxf(m, om);
      z = z*expf(m-M) + oz*expf(om-M);
      m = M;
      ins4(ov0,oi0, av0,av1,av2,av3, ai0,ai1,ai2,ai3);
      ins4(ov1,oi1, av0,av1,av2,av3, ai0,ai1,ai2,ai3);
      ins4(ov2,oi2, av0,av1,av2,av3, ai0,ai1,ai2,ai3);
      ins4(ov3,oi3, av0,av1,av2,av3, ai0,ai1,ai2,ai3);
    }
    if (lane == 0){
      fM[kk]=m; fZ[kk]=z;
      fV[kk*4+0]=av0; fV[kk*4+1]=av1; fV[kk*4+2]=av2; fV[kk*4+3]=av3;
      fI[kk*4+0]=ai0; fI[kk*4+1]=ai1; fI[kk*4+2]=ai2; fI[kk*4+3]=ai3;
    }
  }
  __syncthreads();
  if (tid==0){
    if (t==0){
      #pragma unroll
      for (int j=0;j<4;++j){
        float p = expf(fV[j]-fM[0])/fZ[0];
        scores[b*4+j] = p;
        out[j*(B_N*S_LEN) + b*S_LEN] = fI[j];
        sw[j] = fI[j];
      }
    } else {
      float cv[16]; int cj[16];
      for (int k=0;k<4;++k){
        float s = scores[b*4+k];
        #pragma unroll
        for (int j=0;j<4;++j){
          cv[k*4+j] = expf(fV[k*4+j]-fM[k])/fZ[k]*s;
          cj[k*4+j] = k*V_N + fI[k*4+j];
        }
      }
      bool used[16];
      for (int i=0;i<16;++i) used[i]=false;
      for (int rank=0;rank<4;++rank){
        int best=-1;
        for (int i=0;i<16;++i){
          if (used[i]) continue;
          if (best<0 || cv[i]>cv[best] || (cv[i]==cv[best] && cj[i]<cj[best])) best=i;
        }
        used[best]=true;
        out[rank*(B_N*S_LEN) + b*S_LEN + t] = cj[best];
        sw[rank] = cj[best] % V_N;
      }
    }
  }
  __syncthreads();
  if (t < S_LEN-1){
    const float* ein = enc_inputs  + (size_t)(t+1)*B_N*E_N + (size_t)b*E_N;
    const float* eo  = enc_outputs + (size_t)(t+1)*B_N*H_N + (size_t)b*H_N;
    #pragma unroll
    for (int j=0;j<KBEAM;++j){
      float* xr = xn + (size_t)(j*B_N + b)*D2;
      const float* em = embed + (size_t)sw[j]*E_N;
      xr[tid]       = em[tid];
      xr[E_N + tid] = ein[tid];
      #pragma unroll
      for (int q=0;q<4;++q) xr[2*E_N + q*256 + tid] = eo[q*256 + tid];
    }
  }
}

extern "C" void kernel_launch(void* const* d_in, const int* in_sizes, int n_in,
                              void* d_out, int out_size, void* d_ws, size_t ws_size,
                              hipStream_t stream) {
  (void)in_sizes; (void)n_in; (void)out_size;
  const float* enc_h_n     = (const float*)d_in[0];
  const float* enc_c_n     = (const float*)d_in[1];
  const float* enc_outputs = (const float*)d_in[2];
  const float* enc_inputs  = (const float*)d_in[3];
  const float* embed       = (const float*)d_in[4];
  const float* w_ih        = (const float*)d_in[5];
  const float* w_hh        = (const float*)d_in[6];
  const float* b_lstm      = (const float*)d_in[7];
  const float* w_out       = (const float*)d_in[8];
  const float* b_out       = (const float*)d_in[9];
  int* out = (int*)d_out;

  float* ws = (float*)d_ws;
  const size_t FRONTF = (size_t)R_N*D2*2 + (size_t)R_N*H_N + (size_t)H_N*R_N; // 458752
  const size_t HSPLF  = (size_t)R_N*H_N;        // packed fp16 pair (256 KB)
  const size_t GPARTF = (size_t)NDS*R_N*4096;   // 5,242,880
  const size_t STATF  = (size_t)R_N*NB*10;      // 320,000
  const size_t WSPLF  = (size_t)V_N*H_N;        // packed fp16 pair (128 MB)
  size_t need_split = (FRONTF + HSPLF + GPARTF + STATF + 64 + WSPLF)*sizeof(float);
  bool use_split = (ws_size >= need_split);

  float* xA     = ws;
  float* xB     = xA + (size_t)R_N*D2;
  float* cbuf   = xB + (size_t)R_N*D2;
  float* h2t    = cbuf + (size_t)R_N*H_N;
  f16*   hpk    = (f16*)(h2t + (size_t)H_N*R_N);
  float* big    = h2t + (size_t)H_N*R_N + HSPLF;
  float* gpart  = big;
  float* pm     = big + GPARTF;
  float* pz     = pm + (size_t)R_N*NB;
  float* pv     = pz + (size_t)R_N*NB;
  int*   pi     = (int*)(pv + (size_t)R_N*NB*4);
  float* scoresb= (float*)(pi + (size_t)R_N*NB*4);
  f16*   wpk    = (f16*)(scoresb + 64);

  if (use_split){
    k_convw<<<dim3(V_N/64, H_N/64), 256, 0, stream>>>(w_out, wpk);
  }
  k_init<<<R_N, 256, 0, stream>>>(enc_h_n, enc_c_n, enc_outputs, enc_inputs, embed, xA, cbuf);

  for (int t=0; t<S_LEN; ++t){
    float* xc = (t & 1) ? xB : xA;
    float* xn = (t & 1) ? xA : xB;
    k_gates <<<dim3(64, NDS), 256, 0, stream>>>(xc, w_ih, w_hh, gpart);
    k_lstm  <<<dim3(R_N, 4), 256, 0, stream>>>(gpart, b_lstm, cbuf, xn, h2t, hpk);
    if (use_split){
      k_logits_mfma<<<NB, 256, 0, stream>>>(wpk, hpk, b_out, pm, pz, pv, pi);
    } else {
      k_logits_fused<<<NB, 256, 0, stream>>>(h2t, w_out, b_out, pm, pz, pv, pi);
    }
    k_final <<<B_N, 256, 0, stream>>>(pm, pz, pv, pi, scoresb, out, t, xn,
                                      enc_inputs, enc_outputs, embed);
  }
}

// Round 21
// 2776.949 us; speedup vs baseline: 1.5929x; 1.0271x over previous
//
#include <hip/hip_runtime.h>
#include <math.h>

#define S_LEN 32
#define B_N   16
#define H_N   1024
#define E_N   256
#define V_N   32000
#define KBEAM 4
#define DIN   1536
#define D2    2560   // DIN + H_N
#define R_N   64     // KBEAM * B_N rows of state
#define NDS   20     // K-slices for fp32 fallback gates GEMM
#define GKS   4      // K-slices for MFMA gates (20 sub-slices of 32 each)
#define NB    500    // stats/final col-blocks = V_N/64

typedef _Float16 f16;
typedef f16   f16x8 __attribute__((ext_vector_type(8)));
typedef float f32x4 __attribute__((ext_vector_type(4)));
#define MFMA(A,B,C) __builtin_amdgcn_mfma_f32_16x16x32_f16(A,B,C,0,0,0)

__device__ __forceinline__ float sigmf(float x){ return 1.0f/(1.0f+expf(-x)); }
__device__ __forceinline__ bool better(float v1,int i1,float v2,int i2){
  return (v1>v2) || (v1==v2 && i1<i2);
}
__device__ __forceinline__ void ins4(float bv,int bi,
    float&av0,float&av1,float&av2,float&av3,int&ai0,int&ai1,int&ai2,int&ai3){
  if (better(bv,bi,av3,ai3)){ av3=bv; ai3=bi;
    if (better(av3,ai3,av2,ai2)){ float t=av2;av2=av3;av3=t; int q=ai2;ai2=ai3;ai3=q;
      if (better(av2,ai2,av1,ai1)){ t=av1;av1=av2;av2=t; q=ai1;ai1=ai2;ai2=q;
        if (better(av1,ai1,av0,ai0)){ t=av0;av0=av1;av1=t; q=ai0;ai0=ai1;ai1=q; } } } }
}

// pack one x element (row r, col k in [0,2560)) into xpk fragment layout
__device__ __forceinline__ void packx(f16* xpk, int r, int k, float v){
  int m = r >> 4, lm = r & 15;
  int ks = k >> 5, kq = (k & 31) >> 3, i = k & 7;
  int l = lm + 16*kq;
  size_t base = (((size_t)m*80 + ks)*2)*512 + l*8 + i;
  f16 hh = (f16)v;
  xpk[base]       = hh;
  xpk[base + 512] = (f16)((v - (float)hh)*4096.0f);
}

#define FMA16(w4, h4) { \
  acc[0][0]=fmaf(w4.x,h4.x,acc[0][0]); acc[0][1]=fmaf(w4.x,h4.y,acc[0][1]); \
  acc[0][2]=fmaf(w4.x,h4.z,acc[0][2]); acc[0][3]=fmaf(w4.x,h4.w,acc[0][3]); \
  acc[1][0]=fmaf(w4.y,h4.x,acc[1][0]); acc[1][1]=fmaf(w4.y,h4.y,acc[1][1]); \
  acc[1][2]=fmaf(w4.y,h4.z,acc[1][2]); acc[1][3]=fmaf(w4.y,h4.w,acc[1][3]); \
  acc[2][0]=fmaf(w4.z,h4.x,acc[2][0]); acc[2][1]=fmaf(w4.z,h4.y,acc[2][1]); \
  acc[2][2]=fmaf(w4.z,h4.z,acc[2][2]); acc[2][3]=fmaf(w4.z,h4.w,acc[2][3]); \
  acc[3][0]=fmaf(w4.w,h4.x,acc[3][0]); acc[3][1]=fmaf(w4.w,h4.y,acc[3][1]); \
  acc[3][2]=fmaf(w4.w,h4.z,acc[3][2]); acc[3][3]=fmaf(w4.w,h4.w,acc[3][3]); }

// shared MFMA loop macros (used by logits + gates MFMA kernels; locals must be
// named wp, hp0..hp3, Bh*,Bl*,A0h*..A3l*, c10..c23)
#define LOADSET(S, s) { size_t o_ = (size_t)(s)*1024; \
  Bh##S  = *(const f16x8*)(wp + o_);  Bl##S  = *(const f16x8*)(wp + o_ + 512); \
  A0h##S = *(const f16x8*)(hp0 + o_); A0l##S = *(const f16x8*)(hp0 + o_ + 512); \
  A1h##S = *(const f16x8*)(hp1 + o_); A1l##S = *(const f16x8*)(hp1 + o_ + 512); \
  A2h##S = *(const f16x8*)(hp2 + o_); A2l##S = *(const f16x8*)(hp2 + o_ + 512); \
  A3h##S = *(const f16x8*)(hp3 + o_); A3l##S = *(const f16x8*)(hp3 + o_ + 512); }
#define COMPSET(S) { \
  c10 = MFMA(A0h##S, Bh##S, c10); c20 = MFMA(A0l##S, Bh##S, c20); c20 = MFMA(A0h##S, Bl##S, c20); \
  c11 = MFMA(A1h##S, Bh##S, c11); c21 = MFMA(A1l##S, Bh##S, c21); c21 = MFMA(A1h##S, Bl##S, c21); \
  c12 = MFMA(A2h##S, Bh##S, c12); c22 = MFMA(A2l##S, Bh##S, c22); c22 = MFMA(A2h##S, Bl##S, c22); \
  c13 = MFMA(A3h##S, Bh##S, c13); c23 = MFMA(A3l##S, Bh##S, c23); c23 = MFMA(A3h##S, Bl##S, c23); }
#define DECLFRAGS \
  f32x4 c10={0,0,0,0}, c11={0,0,0,0}, c12={0,0,0,0}, c13={0,0,0,0}; \
  f32x4 c20={0,0,0,0}, c21={0,0,0,0}, c22={0,0,0,0}, c23={0,0,0,0}; \
  f16x8 Bh0,Bl0,A0h0,A1h0,A2h0,A3h0,A0l0,A1l0,A2l0,A3l0; \
  f16x8 Bh1,Bl1,A0h1,A1h1,A2h1,A3h1,A0l1,A1l1,A2l1,A3l1;

// ---- init: x0 (fp32 + packed), c0
__global__ __launch_bounds__(256) void k_init(
    const float* __restrict__ enc_h_n, const float* __restrict__ enc_c_n,
    const float* __restrict__ enc_outputs, const float* __restrict__ enc_inputs,
    const float* __restrict__ embed, float* __restrict__ x, float* __restrict__ c,
    f16* __restrict__ xpk){
  int r = blockIdx.x, tid = threadIdx.x, b = r & 15;
  float* xr = x + (size_t)r*D2;
  float v0 = embed[E_N + tid];
  float v1 = enc_inputs[b*E_N + tid];
  xr[tid]       = v0;
  xr[E_N + tid] = v1;
  float eo[4], hh[4];
  #pragma unroll
  for (int q=0;q<4;++q){
    eo[q] = enc_outputs[b*H_N + q*256 + tid];
    hh[q] = enc_h_n[b*H_N + q*256 + tid];
    xr[2*E_N + q*256 + tid] = eo[q];
    xr[DIN + q*256 + tid]   = hh[q];
    c[(size_t)r*H_N + q*256 + tid] = enc_c_n[b*H_N + q*256 + tid];
  }
  if (xpk){
    packx(xpk, r, tid, v0);
    packx(xpk, r, E_N + tid, v1);
    #pragma unroll
    for (int q=0;q<4;++q){
      packx(xpk, r, 2*E_N + q*256 + tid, eo[q]);
      packx(xpk, r, DIN + q*256 + tid,   hh[q]);
    }
  }
}

// ---- one-time: transpose + split + fragment-pack w_out -> wpk (logits)
__global__ __launch_bounds__(256) void k_convw(
    const float* __restrict__ w, f16* __restrict__ wpk){
  __shared__ f16 Th[64][66];
  __shared__ f16 Tl[64][66];
  int v0 = blockIdx.x*64, d0 = blockIdx.y*64;
  int tid = threadIdx.x;
  int r = tid >> 4, cq = (tid & 15)*4;
  #pragma unroll
  for (int rr=0; rr<4; ++rr){
    int d = r + rr*16;
    float4 x = *(const float4*)&w[(size_t)(d0+d)*V_N + v0 + cq];
    f16 h;
    h=(f16)x.x; Th[d][cq+0]=h; Tl[d][cq+0]=(f16)((x.x-(float)h)*4096.0f);
    h=(f16)x.y; Th[d][cq+1]=h; Tl[d][cq+1]=(f16)((x.y-(float)h)*4096.0f);
    h=(f16)x.z; Th[d][cq+2]=h; Tl[d][cq+2]=(f16)((x.z-(float)h)*4096.0f);
    h=(f16)x.w; Th[d][cq+3]=h; Tl[d][cq+3]=(f16)((x.w-(float)h)*4096.0f);
  }
  __syncthreads();
  int T2 = tid >> 6, l = tid & 63;
  int lm = l & 15, kq = l >> 4;
  int Tg = blockIdx.x*4 + T2;
  #pragma unroll
  for (int ks2=0; ks2<2; ++ks2){
    int ksg = blockIdx.y*2 + ks2;
    f16x8 a, b2;
    #pragma unroll
    for (int i=0;i<8;++i){
      int dd = ks2*32 + kq*8 + i;
      a[i]  = Th[dd][T2*16 + lm];
      b2[i] = Tl[dd][T2*16 + lm];
    }
    size_t base = ((size_t)(Tg*32 + ksg)*2)*512 + l*8;
    *(f16x8*)&wpk[base]       = a;
    *(f16x8*)&wpk[base + 512] = b2;
  }
}

// ---- one-time: transpose + split + fragment-pack [w_ih; w_hh] -> wgpk (gates)
// grid (4096/64, 2560/64) = (64, 40). Tile 64 k x 64 cols. T stride = 80 slices.
__global__ __launch_bounds__(256) void k_convg(
    const float* __restrict__ w_ih, const float* __restrict__ w_hh,
    f16* __restrict__ wgpk){
  __shared__ f16 Th[64][66];
  __shared__ f16 Tl[64][66];
  int c0 = blockIdx.x*64, k0 = blockIdx.y*64;
  int tid = threadIdx.x;
  int r = tid >> 4, cq = (tid & 15)*4;
  #pragma unroll
  for (int rr=0; rr<4; ++rr){
    int d = r + rr*16;
    int row = k0 + d;
    const float* src = (row < DIN) ? &w_ih[(size_t)row*4096 + c0 + cq]
                                   : &w_hh[(size_t)(row-DIN)*4096 + c0 + cq];
    float4 x = *(const float4*)src;
    f16 h;
    h=(f16)x.x; Th[d][cq+0]=h; Tl[d][cq+0]=(f16)((x.x-(float)h)*4096.0f);
    h=(f16)x.y; Th[d][cq+1]=h; Tl[d][cq+1]=(f16)((x.y-(float)h)*4096.0f);
    h=(f16)x.z; Th[d][cq+2]=h; Tl[d][cq+2]=(f16)((x.z-(float)h)*4096.0f);
    h=(f16)x.w; Th[d][cq+3]=h; Tl[d][cq+3]=(f16)((x.w-(float)h)*4096.0f);
  }
  __syncthreads();
  int T2 = tid >> 6, l = tid & 63;
  int lm = l & 15, kq = l >> 4;
  int Tg = blockIdx.x*4 + T2;
  #pragma unroll
  for (int ks2=0; ks2<2; ++ks2){
    int ksg = blockIdx.y*2 + ks2;
    f16x8 a, b2;
    #pragma unroll
    for (int i=0;i<8;++i){
      int dd = ks2*32 + kq*8 + i;
      a[i]  = Th[dd][T2*16 + lm];
      b2[i] = Tl[dd][T2*16 + lm];
    }
    size_t base = (((size_t)Tg*80 + ksg)*2)*512 + l*8;
    *(f16x8*)&wgpk[base]       = a;
    *(f16x8*)&wgpk[base + 512] = b2;
  }
}

// ---- gates via MFMA fp16-split, K-split x4: gpart[4][64][4096]
// grid (64, 4) x 256 thr. Wave = 16 cols x 64 rows x K=640 (20 slices).
__global__ __launch_bounds__(256) void k_gates_mfma(
    const f16* __restrict__ wgpk, const f16* __restrict__ xpk,
    float* __restrict__ gpart){
  int tid = threadIdx.x;
  int lane = tid & 63;
  int wv = tid >> 6;
  int T  = blockIdx.x*4 + wv;
  int ksb = blockIdx.y*20;

  const f16* wp  = wgpk + (((size_t)T*80 + ksb)*2)*512 + lane*8;
  const f16* hp0 = xpk + (((size_t)0*80 + ksb)*2)*512 + lane*8;
  const f16* hp1 = xpk + (((size_t)1*80 + ksb)*2)*512 + lane*8;
  const f16* hp2 = xpk + (((size_t)2*80 + ksb)*2)*512 + lane*8;
  const f16* hp3 = xpk + (((size_t)3*80 + ksb)*2)*512 + lane*8;

  DECLFRAGS

  LOADSET(0, 0)
  for (int s=0; s<20; s+=2){
    LOADSET(1, s+1)
    COMPSET(0)
    if (s+2<20) LOADSET(0, s+2)
    COMPSET(1)
  }

  const float inv = 1.0f/4096.0f;
  int lm = lane & 15;
  int rb = (lane>>4)*4;
  int col = T*16 + lm;
  size_t rbase = (size_t)blockIdx.y*R_N;
#define GSTT(mt, A1, A2) { \
  _Pragma("unroll") for (int rg=0; rg<4; ++rg){ \
    gpart[(rbase + (mt)*16 + rb + rg)*4096 + col] = A1[rg] + A2[rg]*inv; } }
  GSTT(0, c10, c20) GSTT(1, c11, c21) GSTT(2, c12, c22) GSTT(3, c13, c23)
}

// ---- fp32 fallback gates GEMM (round-16 version)
#define GWLD(d, off) (*(const float4*)((((d) < DIN) ? (w_ih + (size_t)(d)*4096) \
                       : (w_hh + (size_t)((d)-DIN)*4096)) + (off)))
__global__ __launch_bounds__(256) void k_gates(
    const float* __restrict__ x, const float* __restrict__ w_ih,
    const float* __restrict__ w_hh, float* __restrict__ gpart){
  int tid = threadIdx.x;
  int jt = blockIdx.x, ks = blockIdx.y;
  int cx = tid & 15, ry = tid >> 4;
  int cb = jt*64;
  int wdd = tid >> 4, wseg = tid & 15;
  int xrow = tid >> 3, xseg = tid & 7;

  __shared__ float Wt0[32][64], Wt1[32][64];
  __shared__ float Xt0[32][68], Xt1[32][68];

  float acc[4][4];
  #pragma unroll
  for (int cc=0;cc<4;++cc)
    #pragma unroll
    for (int rr=0;rr<4;++rr) acc[cc][rr]=0.f;

  int d0 = ks*128;
  const float* xp0 = x + (size_t)xrow*D2 + d0 + xseg*4;
  const float* xp1 = x + (size_t)(xrow+32)*D2 + d0 + xseg*4;

#define GLQ(WA,WB,X0,X1, ch) { int d_ = d0 + (ch)*32; \
  WA = GWLD(d_+wdd,    cb+wseg*4); \
  WB = GWLD(d_+16+wdd, cb+wseg*4); \
  X0 = *(const float4*)(xp0 + (ch)*32); \
  X1 = *(const float4*)(xp1 + (ch)*32); }
#define GSQ(Wt,Xt, WA,WB,X0,X1) { \
  *(float4*)&Wt[wdd][wseg*4]    = WA; \
  *(float4*)&Wt[wdd+16][wseg*4] = WB; \
  Xt[xseg*4+0][xrow] = X0.x; Xt[xseg*4+1][xrow] = X0.y; \
  Xt[xseg*4+2][xrow] = X0.z; Xt[xseg*4+3][xrow] = X0.w; \
  Xt[xseg*4+0][xrow+32] = X1.x; Xt[xseg*4+1][xrow+32] = X1.y; \
  Xt[xseg*4+2][xrow+32] = X1.z; Xt[xseg*4+3][xrow+32] = X1.w; }
#define GCQ(Wt,Xt) { _Pragma("unroll 8") for (int dd=0; dd<32; ++dd){ \
    float4 w4 = *(const float4*)&Wt[dd][cx*4]; \
    float4 h4 = *(const float4*)&Xt[dd][ry*4]; \
    FMA16(w4, h4) } }

  float4 wA0,wB0,x00,x10, wA1,wB1,x01,x11;
  GLQ(wA0,wB0,x00,x10, 0)
  GSQ(Wt0,Xt0, wA0,wB0,x00,x10)
  GLQ(wA1,wB1,x01,x11, 1)
  __syncthreads();

  for (int ch=0; ch<4; ch+=2){
    if (ch+2<4) GLQ(wA0,wB0,x00,x10, ch+2)
    GSQ(Wt1,Xt1, wA1,wB1,x01,x11)
    GCQ(Wt0,Xt0)
    __syncthreads();
    if (ch+3<4) GLQ(wA1,wB1,x01,x11, ch+3)
    if (ch+2<4) GSQ(Wt0,Xt0, wA0,wB0,x00,x10)
    GCQ(Wt1,Xt1)
    if (ch+2<4) __syncthreads();
  }
  #pragma unroll
  for (int rr=0;rr<4;++rr){
    float4 o; o.x=acc[0][rr]; o.y=acc[1][rr]; o.z=acc[2][rr]; o.w=acc[3][rr];
    *(float4*)&gpart[((size_t)(ks*R_N + ry*4+rr))*4096 + cb + cx*4] = o;
  }
}

// ---- LSTM: sum nds partial slices + bias, cell update; emit h (fp32 + packs)
__global__ __launch_bounds__(256) void k_lstm(
    const float* __restrict__ gpart, const float* __restrict__ b_lstm,
    float* __restrict__ c, float* __restrict__ xn, float* __restrict__ h2t,
    f16* __restrict__ hpk, f16* __restrict__ xpk, int nds){
  int r = blockIdx.x, tid = threadIdx.x;
  int j = blockIdx.y*256 + tid;
  float gi = b_lstm[j], gf = b_lstm[1024+j], gg = b_lstm[2048+j], go = b_lstm[3072+j];
  for (int ds=0; ds<nds; ++ds){
    size_t base = ((size_t)ds*R_N + r)*4096;
    gi += gpart[base + j];      gf += gpart[base + 1024 + j];
    gg += gpart[base + 2048+j]; go += gpart[base + 3072 + j];
  }
  float cv = c[(size_t)r*H_N + j];
  float c2 = sigmf(gf)*cv + sigmf(gi)*tanhf(gg);
  float h2 = sigmf(go)*tanhf(c2);
  c[(size_t)r*H_N + j] = c2;
  xn[(size_t)r*D2 + DIN + j] = h2;
  h2t[(size_t)j*R_N + r] = h2;
  if (hpk){
    f16 hh = (f16)h2;
    int m = r >> 4, lm = r & 15;
    int ks = j >> 5, kq = (j & 31) >> 3, i = j & 7;
    int l = lm + 16*kq;
    size_t base2 = ((size_t)(m*32 + ks)*2)*512 + l*8 + i;
    hpk[base2]       = hh;
    hpk[base2 + 512] = (f16)((h2 - (float)hh)*4096.0f);
    packx(xpk, r, DIN + j, h2);
  }
}

// ---- logits via MFMA fp16-split (K=1024) + fused in-LDS stats.
__global__ __launch_bounds__(256) void k_logits_mfma(
    const f16* __restrict__ wpk, const f16* __restrict__ hpk,
    const float* __restrict__ b_out,
    float* __restrict__ pm, float* __restrict__ pz,
    float* __restrict__ pv, int* __restrict__ pi){
  int tid = threadIdx.x;
  int lane = tid & 63;
  int wv = tid >> 6;
  int T  = blockIdx.x*4 + wv;
  int vb = T*16;

  const f16* wp  = wpk + ((size_t)(T*32))*2*512 + lane*8;
  const f16* hp0 = hpk + ((size_t)(0*32))*2*512 + lane*8;
  const f16* hp1 = hpk + ((size_t)(1*32))*2*512 + lane*8;
  const f16* hp2 = hpk + ((size_t)(2*32))*2*512 + lane*8;
  const f16* hp3 = hpk + ((size_t)(3*32))*2*512 + lane*8;

  DECLFRAGS

  LOADSET(0, 0)
  for (int s=0; s<32; s+=2){
    LOADSET(1, s+1)
    COMPSET(0)
    if (s+2<32) LOADSET(0, s+2)
    COMPSET(1)
  }

  __shared__ float Ls[64][68];

  const float inv = 1.0f/4096.0f;
  int lm = lane & 15;
  int rb = (lane>>4)*4;
  float bias = b_out[vb + lm];
#define STT(mt, A1, A2) { \
  _Pragma("unroll") for (int rg=0; rg<4; ++rg){ \
    Ls[(mt)*16 + rb + rg][wv*16 + lm] = A1[rg] + A2[rg]*inv + bias; } }
  STT(0, c10, c20) STT(1, c11, c21) STT(2, c12, c22) STT(3, c13, c23)
  __syncthreads();

  int cx = tid & 15, ry = tid >> 4;
  int cb = blockIdx.x * 64;
  #pragma unroll
  for (int rr=0;rr<4;++rr){
    int row = ry*4 + rr;
    float v0 = Ls[row][cx*4+0], v1 = Ls[row][cx*4+1];
    float v2 = Ls[row][cx*4+2], v3 = Ls[row][cx*4+3];
    int   c0i = cb + cx*4;
    float tv0=-INFINITY,tv1=-INFINITY,tv2=-INFINITY,tv3=-INFINITY;
    int   ti0=0x7fffffff,ti1=0x7fffffff,ti2=0x7fffffff,ti3=0x7fffffff;
    ins4(v0,c0i+0,tv0,tv1,tv2,tv3,ti0,ti1,ti2,ti3);
    ins4(v1,c0i+1,tv0,tv1,tv2,tv3,ti0,ti1,ti2,ti3);
    ins4(v2,c0i+2,tv0,tv1,tv2,tv3,ti0,ti1,ti2,ti3);
    ins4(v3,c0i+3,tv0,tv1,tv2,tv3,ti0,ti1,ti2,ti3);
    float z = expf(v0-tv0)+expf(v1-tv0)+expf(v2-tv0)+expf(v3-tv0);
    #pragma unroll
    for (int msk=1; msk<16; msk<<=1){
      float om  = __shfl_xor(tv0, msk, 16);
      float oz  = __shfl_xor(z,   msk, 16);
      float ov1 = __shfl_xor(tv1, msk, 16);
      float ov2 = __shfl_xor(tv2, msk, 16);
      float ov3 = __shfl_xor(tv3, msk, 16);
      int   oi0 = __shfl_xor(ti0, msk, 16);
      int   oi1 = __shfl_xor(ti1, msk, 16);
      int   oi2 = __shfl_xor(ti2, msk, 16);
      int   oi3 = __shfl_xor(ti3, msk, 16);
      float M = fmaxf(tv0, om);
      z = z*expf(tv0-M) + oz*expf(om-M);
      ins4(om, oi0, tv0,tv1,tv2,tv3, ti0,ti1,ti2,ti3);
      ins4(ov1,oi1, tv0,tv1,tv2,tv3, ti0,ti1,ti2,ti3);
      ins4(ov2,oi2, tv0,tv1,tv2,tv3, ti0,ti1,ti2,ti3);
      ins4(ov3,oi3, tv0,tv1,tv2,tv3, ti0,ti1,ti2,ti3);
    }
    if (cx == 0){
      size_t base = (size_t)row*NB + blockIdx.x;
      pm[base]=tv0; pz[base]=z;
      pv[base*4+0]=tv0; pv[base*4+1]=tv1; pv[base*4+2]=tv2; pv[base*4+3]=tv3;
      pi[base*4+0]=ti0; pi[base*4+1]=ti1; pi[base*4+2]=ti2; pi[base*4+3]=ti3;
    }
  }
}

// ---- fp32 fallback fused logits+stats
__global__ __launch_bounds__(256) void k_logits_fused(
    const float* __restrict__ h2t, const float* __restrict__ w_out,
    const float* __restrict__ b_out,
    float* __restrict__ pm, float* __restrict__ pz,
    float* __restrict__ pv, int* __restrict__ pi){
  int tid = threadIdx.x;
  int cx  = tid & 15, ry = tid >> 4;
  int cb  = blockIdx.x * 64;
  int sdd = tid >> 4, seg = tid & 15;
  __shared__ float Wt[32][64];
  __shared__ float Ht[32][64];
  float acc[4][4];
  #pragma unroll
  for (int cc=0;cc<4;++cc)
    #pragma unroll
    for (int rr=0;rr<4;++rr) acc[cc][rr]=0.f;
  const float* gW = w_out + (size_t)sdd*V_N + cb + seg*4;
  const float* gH = h2t + sdd*64 + seg*4;
#define FLQ(WA,WB,HA,HB, ch) { \
  const float* gWn = gW + (size_t)(ch)*32*V_N; \
  const float* gHn = gH + (size_t)(ch)*32*64; \
  WA = *(const float4*)gWn; WB = *(const float4*)(gWn + (size_t)16*V_N); \
  HA = *(const float4*)gHn; HB = *(const float4*)(gHn + 16*64); }
#define FSQ(WA,WB,HA,HB) { \
  *(float4*)&Wt[sdd][seg*4]    = WA; \
  *(float4*)&Wt[sdd+16][seg*4] = WB; \
  *(float4*)&Ht[sdd][seg*4]    = HA; \
  *(float4*)&Ht[sdd+16][seg*4] = HB; }
#define FCQ() { _Pragma("unroll 8") for (int dd=0; dd<32; ++dd){ \
    float4 w4 = *(const float4*)&Wt[dd][cx*4]; \
    float4 h4 = *(const float4*)&Ht[dd][ry*4]; \
    FMA16(w4, h4) } }
  float4 wA0,wB0,hA0,hB0, wA1,wB1,hA1,hB1;
  FLQ(wA0,wB0,hA0,hB0, 0)
  FSQ(wA0,wB0,hA0,hB0)
  FLQ(wA1,wB1,hA1,hB1, 1)
  __syncthreads();
  for (int ch=0; ch<32; ch+=2){
    if (ch+2<32) FLQ(wA0,wB0,hA0,hB0, ch+2)
    FCQ()
    __syncthreads();
    FSQ(wA1,wB1,hA1,hB1)
    __syncthreads();
    if (ch+3<32) FLQ(wA1,wB1,hA1,hB1, ch+3)
    FCQ()
    if (ch+2<32){
      __syncthreads();
      FSQ(wA0,wB0,hA0,hB0)
      __syncthreads();
    }
  }
  float4 bias = *(const float4*)&b_out[cb + cx*4];
  #pragma unroll
  for (int rr=0;rr<4;++rr){
    float v0 = acc[0][rr]+bias.x, v1 = acc[1][rr]+bias.y;
    float v2 = acc[2][rr]+bias.z, v3 = acc[3][rr]+bias.w;
    int   c0i = cb + cx*4;
    float tv0=-INFINITY,tv1=-INFINITY,tv2=-INFINITY,tv3=-INFINITY;
    int   ti0=0x7fffffff,ti1=0x7fffffff,ti2=0x7fffffff,ti3=0x7fffffff;
    ins4(v0,c0i+0,tv0,tv1,tv2,tv3,ti0,ti1,ti2,ti3);
    ins4(v1,c0i+1,tv0,tv1,tv2,tv3,ti0,ti1,ti2,ti3);
    ins4(v2,c0i+2,tv0,tv1,tv2,tv3,ti0,ti1,ti2,ti3);
    ins4(v3,c0i+3,tv0,tv1,tv2,tv3,ti0,ti1,ti2,ti3);
    float z = expf(v0-tv0)+expf(v1-tv0)+expf(v2-tv0)+expf(v3-tv0);
    #pragma unroll
    for (int msk=1; msk<16; msk<<=1){
      float om  = __shfl_xor(tv0, msk, 16);
      float oz  = __shfl_xor(z,   msk, 16);
      float ov1 = __shfl_xor(tv1, msk, 16);
      float ov2 = __shfl_xor(tv2, msk, 16);
      float ov3 = __shfl_xor(tv3, msk, 16);
      int   oi0 = __shfl_xor(ti0, msk, 16);
      int   oi1 = __shfl_xor(ti1, msk, 16);
      int   oi2 = __shfl_xor(ti2, msk, 16);
      int   oi3 = __shfl_xor(ti3, msk, 16);
      float M = fmaxf(tv0, om);
      z = z*expf(tv0-M) + oz*expf(om-M);
      ins4(om, oi0, tv0,tv1,tv2,tv3, ti0,ti1,ti2,ti3);
      ins4(ov1,oi1, tv0,tv1,tv2,tv3, ti0,ti1,ti2,ti3);
      ins4(ov2,oi2, tv0,tv1,tv2,tv3, ti0,ti1,ti2,ti3);
      ins4(ov3,oi3, tv0,tv1,tv2,tv3, ti0,ti1,ti2,ti3);
    }
    if (cx == 0){
      int row = ry*4 + rr;
      size_t base = (size_t)row*NB + blockIdx.x;
      pm[base]=tv0; pz[base]=z;
      pv[base*4+0]=tv0; pv[base*4+1]=tv1; pv[base*4+2]=tv2; pv[base*4+3]=tv3;
      pi[base*4+0]=ti0; pi[base*4+1]=ti1; pi[base*4+2]=ti2; pi[base*4+3]=ti3;
    }
  }
}

// ---- final: per-beam wave reduce + joint top-4 + next-x assembly (+pack)
__global__ __launch_bounds__(256) void k_final(
    const float* __restrict__ pm, const float* __restrict__ pz,
    const float* __restrict__ pv, const int* __restrict__ pi,
    float* __restrict__ scores, int* __restrict__ out, int t,
    float* __restrict__ xn, f16* __restrict__ xpk,
    const float* __restrict__ enc_inputs, const float* __restrict__ enc_outputs,
    const float* __restrict__ embed){
  int b = blockIdx.x, tid = threadIdx.x;
  int kk = tid >> 6, lane = tid & 63;
  __shared__ float fM[KBEAM], fZ[KBEAM], fV[16];
  __shared__ int   fI[16], sw[KBEAM];
  int nk = (t==0) ? 1 : KBEAM;
  if (kk < nk){
    size_t rb = (size_t)(kk*B_N + b)*NB;
    float m=-INFINITY, z=0.f;
    float av0=-INFINITY,av1=-INFINITY,av2=-INFINITY,av3=-INFINITY;
    int   ai0=0x7fffffff,ai1=0x7fffffff,ai2=0x7fffffff,ai3=0x7fffffff;
    for (int p0=lane; p0<NB; p0+=64){
      size_t p = rb + p0;
      float mf = pm[p];
      float M = fmaxf(m, mf);
      z = z*expf(m-M) + pz[p]*expf(mf-M);
      m = M;
      #pragma unroll
      for (int q=0;q<4;++q)
        ins4(pv[p*4+q], pi[p*4+q], av0,av1,av2,av3, ai0,ai1,ai2,ai3);
    }
    #pragma unroll
    for (int msk=1; msk<64; msk<<=1){
      float om  = __shfl_xor(m,   msk);
      float oz  = __shfl_xor(z,   msk);
      float ov0 = __shfl_xor(av0, msk);
      float ov1 = __shfl_xor(av1, msk);
      float ov2 = __shfl_xor(av2, msk);
      float ov3 = __shfl_xor(av3, msk);
      int   oi0 = __shfl_xor(ai0, msk);
      int   oi1 = __shfl_xor(ai1, msk);
      int   oi2 = __shfl_xor(ai2, msk);
      int   oi3 = __shfl_xor(ai3, msk);
      float M = fmaxf(m, om);
      z = z*expf(m-M) + oz*expf(om-M);
      m = M;
      ins4(ov0,oi0, av0,av1,av2,av3, ai0,ai1,ai2,ai3);
      ins4(ov1,oi1, av0,av1,av2,av3, ai0,ai1,ai2,ai3);
      ins4(ov2,oi2, av0,av1,av2,av3, ai0,ai1,ai2,ai3);
      ins4(ov3,oi3, av0,av1,av2,av3, ai0,ai1,ai2,ai3);
    }
    if (lane == 0){
      fM[kk]=m; fZ[kk]=z;
      fV[kk*4+0]=av0; fV[kk*4+1]=av1; fV[kk*4+2]=av2; fV[kk*4+3]=av3;
      fI[kk*4+0]=ai0; fI[kk*4+1]=ai1; fI[kk*4+2]=ai2; fI[kk*4+3]=ai3;
    }
  }
  __syncthreads();
  if (tid==0){
    if (t==0){
      #pragma unroll
      for (int j=0;j<4;++j){
        float p = expf(fV[j]-fM[0])/fZ[0];
        scores[b*4+j] = p;
        out[j*(B_N*S_LEN) + b*S_LEN] = fI[j];
        sw[j] = fI[j];
      }
    } else {
      float cv[16]; int cj[16];
      for (int k=0;k<4;++k){
        float s = scores[b*4+k];
        #pragma unroll
        for (int j=0;j<4;++j){
          cv[k*4+j] = expf(fV[k*4+j]-fM[k])/fZ[k]*s;
          cj[k*4+j] = k*V_N + fI[k*4+j];
        }
      }
      bool used[16];
      for (int i=0;i<16;++i) used[i]=false;
      for (int rank=0;rank<4;++rank){
        int best=-1;
        for (int i=0;i<16;++i){
          if (used[i]) continue;
          if (best<0 || cv[i]>cv[best] || (cv[i]==cv[best] && cj[i]<cj[best])) best=i;
        }
        used[best]=true;
        out[rank*(B_N*S_LEN) + b*S_LEN + t] = cj[best];
        sw[rank] = cj[best] % V_N;
      }
    }
  }
  __syncthreads();
  if (t < S_LEN-1){
    const float* ein = enc_inputs  + (size_t)(t+1)*B_N*E_N + (size_t)b*E_N;
    const float* eo  = enc_outputs + (size_t)(t+1)*B_N*H_N + (size_t)b*H_N;
    #pragma unroll
    for (int j=0;j<KBEAM;++j){
      int r = j*B_N + b;
      float* xr = xn + (size_t)r*D2;
      const float* em = embed + (size_t)sw[j]*E_N;
      float v0 = em[tid], v1 = ein[tid];
      xr[tid]       = v0;
      xr[E_N + tid] = v1;
      if (xpk){ packx(xpk, r, tid, v0); packx(xpk, r, E_N + tid, v1); }
      #pragma unroll
      for (int q=0;q<4;++q){
        float v = eo[q*256 + tid];
        xr[2*E_N + q*256 + tid] = v;
        if (xpk) packx(xpk, r, 2*E_N + q*256 + tid, v);
      }
    }
  }
}

extern "C" void kernel_launch(void* const* d_in, const int* in_sizes, int n_in,
                              void* d_out, int out_size, void* d_ws, size_t ws_size,
                              hipStream_t stream) {
  (void)in_sizes; (void)n_in; (void)out_size;
  const float* enc_h_n     = (const float*)d_in[0];
  const float* enc_c_n     = (const float*)d_in[1];
  const float* enc_outputs = (const float*)d_in[2];
  const float* enc_inputs  = (const float*)d_in[3];
  const float* embed       = (const float*)d_in[4];
  const float* w_ih        = (const float*)d_in[5];
  const float* w_hh        = (const float*)d_in[6];
  const float* b_lstm      = (const float*)d_in[7];
  const float* w_out       = (const float*)d_in[8];
  const float* b_out       = (const float*)d_in[9];
  int* out = (int*)d_out;

  float* ws = (float*)d_ws;
  const size_t FRONTF = (size_t)R_N*D2*2 + (size_t)R_N*H_N + (size_t)H_N*R_N; // 458752
  const size_t HSPLF  = (size_t)R_N*H_N;         // hpk: packed fp16 pair
  const size_t XPKF   = (size_t)R_N*D2;          // xpk: packed fp16 pair (64x2560)
  const size_t GPARTF = (size_t)NDS*R_N*4096;    // 5,242,880 (fallback max)
  const size_t STATF  = (size_t)R_N*NB*10;       // 320,000
  const size_t WSPLF  = (size_t)V_N*H_N;         // wpk pair (128 MB)
  const size_t WGPKF  = (size_t)D2*4096;         // wgpk pair (42 MB)
  size_t need_split = (FRONTF + HSPLF + XPKF + GPARTF + STATF + 64 + WSPLF + WGPKF)*sizeof(float);
  bool use_split = (ws_size >= need_split);

  float* xA     = ws;
  float* xB     = xA + (size_t)R_N*D2;
  float* cbuf   = xB + (size_t)R_N*D2;
  float* h2t    = cbuf + (size_t)R_N*H_N;
  f16*   hpk    = (f16*)(h2t + (size_t)H_N*R_N);
  f16*   xpk    = (f16*)(h2t + (size_t)H_N*R_N + HSPLF);
  float* big    = h2t + (size_t)H_N*R_N + HSPLF + XPKF;
  float* gpart  = big;
  float* pm     = big + GPARTF;
  float* pz     = pm + (size_t)R_N*NB;
  float* pv     = pz + (size_t)R_N*NB;
  int*   pi     = (int*)(pv + (size_t)R_N*NB*4);
  float* scoresb= (float*)(pi + (size_t)R_N*NB*4);
  f16*   wpk    = (f16*)(scoresb + 64);
  f16*   wgpk   = (f16*)((float*)(scoresb + 64) + WSPLF);

  f16* hpk_arg = use_split ? hpk : (f16*)0;
  f16* xpk_arg = use_split ? xpk : (f16*)0;

  if (use_split){
    k_convw<<<dim3(V_N/64, H_N/64), 256, 0, stream>>>(w_out, wpk);
    k_convg<<<dim3(4096/64, D2/64), 256, 0, stream>>>(w_ih, w_hh, wgpk);
  }
  k_init<<<R_N, 256, 0, stream>>>(enc_h_n, enc_c_n, enc_outputs, enc_inputs,
                                  embed, xA, cbuf, xpk_arg);

  for (int t=0; t<S_LEN; ++t){
    float* xc = (t & 1) ? xB : xA;
    float* xn = (t & 1) ? xA : xB;
    if (use_split){
      k_gates_mfma<<<dim3(64, GKS), 256, 0, stream>>>(wgpk, xpk, gpart);
      k_lstm<<<dim3(R_N, 4), 256, 0, stream>>>(gpart, b_lstm, cbuf, xn, h2t,
                                               hpk_arg, xpk_arg, GKS);
      k_logits_mfma<<<NB, 256, 0, stream>>>(wpk, hpk, b_out, pm, pz, pv, pi);
    } else {
      k_gates <<<dim3(64, NDS), 256, 0, stream>>>(xc, w_ih, w_hh, gpart);
      k_lstm<<<dim3(R_N, 4), 256, 0, stream>>>(gpart, b_lstm, cbuf, xn, h2t,
                                               (f16*)0, (f16*)0, NDS);
      k_logits_fused<<<NB, 256, 0, stream>>>(h2t, w_out, b_out, pm, pz, pv, pi);
    }
    k_final <<<B_N, 256, 0, stream>>>(pm, pz, pv, pi, scoresb, out, t, xn, xpk_arg,
                                      enc_inputs, enc_outputs, embed);
  }
}

// Round 22
// 2712.459 us; speedup vs baseline: 1.6308x; 1.0238x over previous
//
#include <hip/hip_runtime.h>
#include <math.h>

#define S_LEN 32
#define B_N   16
#define H_N   1024
#define E_N   256
#define V_N   32000
#define KBEAM 4
#define DIN   1536
#define D2    2560   // DIN + H_N
#define R_N   64     // KBEAM * B_N rows of state
#define NDS   20     // K-slices for fp32 fallback gates GEMM
#define GKS   4      // K-slices for MFMA gates (20 sub-slices of 32 each)
#define NB    500    // stats/final col-blocks = V_N/64

typedef _Float16 f16;
typedef f16   f16x8 __attribute__((ext_vector_type(8)));
typedef float f32x4 __attribute__((ext_vector_type(4)));
#define MFMA(A,B,C) __builtin_amdgcn_mfma_f32_16x16x32_f16(A,B,C,0,0,0)

__device__ __forceinline__ float sigmf(float x){ return 1.0f/(1.0f+expf(-x)); }
__device__ __forceinline__ bool better(float v1,int i1,float v2,int i2){
  return (v1>v2) || (v1==v2 && i1<i2);
}
__device__ __forceinline__ void ins4(float bv,int bi,
    float&av0,float&av1,float&av2,float&av3,int&ai0,int&ai1,int&ai2,int&ai3){
  if (better(bv,bi,av3,ai3)){ av3=bv; ai3=bi;
    if (better(av3,ai3,av2,ai2)){ float t=av2;av2=av3;av3=t; int q=ai2;ai2=ai3;ai3=q;
      if (better(av2,ai2,av1,ai1)){ t=av1;av1=av2;av2=t; q=ai1;ai1=ai2;ai2=q;
        if (better(av1,ai1,av0,ai0)){ t=av0;av0=av1;av1=t; q=ai0;ai0=ai1;ai1=q; } } } }
}

// pack one x element (row r, col k in [0,2560)) into xpk fragment layout
__device__ __forceinline__ void packx(f16* xpk, int r, int k, float v){
  int m = r >> 4, lm = r & 15;
  int ks = k >> 5, kq = (k & 31) >> 3, i = k & 7;
  int l = lm + 16*kq;
  size_t base = (((size_t)m*80 + ks)*2)*512 + l*8 + i;
  f16 hh = (f16)v;
  xpk[base]       = hh;
  xpk[base + 512] = (f16)((v - (float)hh)*4096.0f);
}

#define FMA16(w4, h4) { \
  acc[0][0]=fmaf(w4.x,h4.x,acc[0][0]); acc[0][1]=fmaf(w4.x,h4.y,acc[0][1]); \
  acc[0][2]=fmaf(w4.x,h4.z,acc[0][2]); acc[0][3]=fmaf(w4.x,h4.w,acc[0][3]); \
  acc[1][0]=fmaf(w4.y,h4.x,acc[1][0]); acc[1][1]=fmaf(w4.y,h4.y,acc[1][1]); \
  acc[1][2]=fmaf(w4.y,h4.z,acc[1][2]); acc[1][3]=fmaf(w4.y,h4.w,acc[1][3]); \
  acc[2][0]=fmaf(w4.z,h4.x,acc[2][0]); acc[2][1]=fmaf(w4.z,h4.y,acc[2][1]); \
  acc[2][2]=fmaf(w4.z,h4.z,acc[2][2]); acc[2][3]=fmaf(w4.z,h4.w,acc[2][3]); \
  acc[3][0]=fmaf(w4.w,h4.x,acc[3][0]); acc[3][1]=fmaf(w4.w,h4.y,acc[3][1]); \
  acc[3][2]=fmaf(w4.w,h4.z,acc[3][2]); acc[3][3]=fmaf(w4.w,h4.w,acc[3][3]); }

#define LOADSET(S, s) { size_t o_ = (size_t)(s)*1024; \
  Bh##S  = *(const f16x8*)(wp + o_);  Bl##S  = *(const f16x8*)(wp + o_ + 512); \
  A0h##S = *(const f16x8*)(hp0 + o_); A0l##S = *(const f16x8*)(hp0 + o_ + 512); \
  A1h##S = *(const f16x8*)(hp1 + o_); A1l##S = *(const f16x8*)(hp1 + o_ + 512); \
  A2h##S = *(const f16x8*)(hp2 + o_); A2l##S = *(const f16x8*)(hp2 + o_ + 512); \
  A3h##S = *(const f16x8*)(hp3 + o_); A3l##S = *(const f16x8*)(hp3 + o_ + 512); }
#define COMPSET(S) { \
  c10 = MFMA(A0h##S, Bh##S, c10); c20 = MFMA(A0l##S, Bh##S, c20); c20 = MFMA(A0h##S, Bl##S, c20); \
  c11 = MFMA(A1h##S, Bh##S, c11); c21 = MFMA(A1l##S, Bh##S, c21); c21 = MFMA(A1h##S, Bl##S, c21); \
  c12 = MFMA(A2h##S, Bh##S, c12); c22 = MFMA(A2l##S, Bh##S, c22); c22 = MFMA(A2h##S, Bl##S, c22); \
  c13 = MFMA(A3h##S, Bh##S, c13); c23 = MFMA(A3l##S, Bh##S, c23); c23 = MFMA(A3h##S, Bl##S, c23); }
#define DECLFRAGS \
  f32x4 c10={0,0,0,0}, c11={0,0,0,0}, c12={0,0,0,0}, c13={0,0,0,0}; \
  f32x4 c20={0,0,0,0}, c21={0,0,0,0}, c22={0,0,0,0}, c23={0,0,0,0}; \
  f16x8 Bh0,Bl0,A0h0,A1h0,A2h0,A3h0,A0l0,A1l0,A2l0,A3l0; \
  f16x8 Bh1,Bl1,A0h1,A1h1,A2h1,A3h1,A0l1,A1l1,A2l1,A3l1;

// ---- init: x0 (fp32 + packed), c0
__global__ __launch_bounds__(256) void k_init(
    const float* __restrict__ enc_h_n, const float* __restrict__ enc_c_n,
    const float* __restrict__ enc_outputs, const float* __restrict__ enc_inputs,
    const float* __restrict__ embed, float* __restrict__ x, float* __restrict__ c,
    f16* __restrict__ xpk){
  int r = blockIdx.x, tid = threadIdx.x, b = r & 15;
  float* xr = x + (size_t)r*D2;
  float v0 = embed[E_N + tid];
  float v1 = enc_inputs[b*E_N + tid];
  xr[tid]       = v0;
  xr[E_N + tid] = v1;
  float eo[4], hh[4];
  #pragma unroll
  for (int q=0;q<4;++q){
    eo[q] = enc_outputs[b*H_N + q*256 + tid];
    hh[q] = enc_h_n[b*H_N + q*256 + tid];
    xr[2*E_N + q*256 + tid] = eo[q];
    xr[DIN + q*256 + tid]   = hh[q];
    c[(size_t)r*H_N + q*256 + tid] = enc_c_n[b*H_N + q*256 + tid];
  }
  if (xpk){
    packx(xpk, r, tid, v0);
    packx(xpk, r, E_N + tid, v1);
    #pragma unroll
    for (int q=0;q<4;++q){
      packx(xpk, r, 2*E_N + q*256 + tid, eo[q]);
      packx(xpk, r, DIN + q*256 + tid,   hh[q]);
    }
  }
}

// ---- one-time: transpose + split + fragment-pack w_out -> wpk (logits)
__global__ __launch_bounds__(256) void k_convw(
    const float* __restrict__ w, f16* __restrict__ wpk){
  __shared__ f16 Th[64][66];
  __shared__ f16 Tl[64][66];
  int v0 = blockIdx.x*64, d0 = blockIdx.y*64;
  int tid = threadIdx.x;
  int r = tid >> 4, cq = (tid & 15)*4;
  #pragma unroll
  for (int rr=0; rr<4; ++rr){
    int d = r + rr*16;
    float4 x = *(const float4*)&w[(size_t)(d0+d)*V_N + v0 + cq];
    f16 h;
    h=(f16)x.x; Th[d][cq+0]=h; Tl[d][cq+0]=(f16)((x.x-(float)h)*4096.0f);
    h=(f16)x.y; Th[d][cq+1]=h; Tl[d][cq+1]=(f16)((x.y-(float)h)*4096.0f);
    h=(f16)x.z; Th[d][cq+2]=h; Tl[d][cq+2]=(f16)((x.z-(float)h)*4096.0f);
    h=(f16)x.w; Th[d][cq+3]=h; Tl[d][cq+3]=(f16)((x.w-(float)h)*4096.0f);
  }
  __syncthreads();
  int T2 = tid >> 6, l = tid & 63;
  int lm = l & 15, kq = l >> 4;
  int Tg = blockIdx.x*4 + T2;
  #pragma unroll
  for (int ks2=0; ks2<2; ++ks2){
    int ksg = blockIdx.y*2 + ks2;
    f16x8 a, b2;
    #pragma unroll
    for (int i=0;i<8;++i){
      int dd = ks2*32 + kq*8 + i;
      a[i]  = Th[dd][T2*16 + lm];
      b2[i] = Tl[dd][T2*16 + lm];
    }
    size_t base = ((size_t)(Tg*32 + ksg)*2)*512 + l*8;
    *(f16x8*)&wpk[base]       = a;
    *(f16x8*)&wpk[base + 512] = b2;
  }
}

// ---- one-time: transpose + split + fragment-pack [w_ih; w_hh] -> wgpk (gates)
__global__ __launch_bounds__(256) void k_convg(
    const float* __restrict__ w_ih, const float* __restrict__ w_hh,
    f16* __restrict__ wgpk){
  __shared__ f16 Th[64][66];
  __shared__ f16 Tl[64][66];
  int c0 = blockIdx.x*64, k0 = blockIdx.y*64;
  int tid = threadIdx.x;
  int r = tid >> 4, cq = (tid & 15)*4;
  #pragma unroll
  for (int rr=0; rr<4; ++rr){
    int d = r + rr*16;
    int row = k0 + d;
    const float* src = (row < DIN) ? &w_ih[(size_t)row*4096 + c0 + cq]
                                   : &w_hh[(size_t)(row-DIN)*4096 + c0 + cq];
    float4 x = *(const float4*)src;
    f16 h;
    h=(f16)x.x; Th[d][cq+0]=h; Tl[d][cq+0]=(f16)((x.x-(float)h)*4096.0f);
    h=(f16)x.y; Th[d][cq+1]=h; Tl[d][cq+1]=(f16)((x.y-(float)h)*4096.0f);
    h=(f16)x.z; Th[d][cq+2]=h; Tl[d][cq+2]=(f16)((x.z-(float)h)*4096.0f);
    h=(f16)x.w; Th[d][cq+3]=h; Tl[d][cq+3]=(f16)((x.w-(float)h)*4096.0f);
  }
  __syncthreads();
  int T2 = tid >> 6, l = tid & 63;
  int lm = l & 15, kq = l >> 4;
  int Tg = blockIdx.x*4 + T2;
  #pragma unroll
  for (int ks2=0; ks2<2; ++ks2){
    int ksg = blockIdx.y*2 + ks2;
    f16x8 a, b2;
    #pragma unroll
    for (int i=0;i<8;++i){
      int dd = ks2*32 + kq*8 + i;
      a[i]  = Th[dd][T2*16 + lm];
      b2[i] = Tl[dd][T2*16 + lm];
    }
    size_t base = (((size_t)Tg*80 + ksg)*2)*512 + l*8;
    *(f16x8*)&wgpk[base]       = a;
    *(f16x8*)&wgpk[base + 512] = b2;
  }
}

// ---- gates via MFMA fp16-split, K-split x4: gpart[4][64][4096]
__global__ __launch_bounds__(256) void k_gates_mfma(
    const f16* __restrict__ wgpk, const f16* __restrict__ xpk,
    float* __restrict__ gpart){
  int tid = threadIdx.x;
  int lane = tid & 63;
  int wv = tid >> 6;
  int T  = blockIdx.x*4 + wv;
  int ksb = blockIdx.y*20;

  const f16* wp  = wgpk + (((size_t)T*80 + ksb)*2)*512 + lane*8;
  const f16* hp0 = xpk + (((size_t)0*80 + ksb)*2)*512 + lane*8;
  const f16* hp1 = xpk + (((size_t)1*80 + ksb)*2)*512 + lane*8;
  const f16* hp2 = xpk + (((size_t)2*80 + ksb)*2)*512 + lane*8;
  const f16* hp3 = xpk + (((size_t)3*80 + ksb)*2)*512 + lane*8;

  DECLFRAGS

  LOADSET(0, 0)
  for (int s=0; s<20; s+=2){
    LOADSET(1, s+1)
    COMPSET(0)
    if (s+2<20) LOADSET(0, s+2)
    COMPSET(1)
  }

  const float inv = 1.0f/4096.0f;
  int lm = lane & 15;
  int rb = (lane>>4)*4;
  int col = T*16 + lm;
  size_t rbase = (size_t)blockIdx.y*R_N;
#define GSTT(mt, A1, A2) { \
  _Pragma("unroll") for (int rg=0; rg<4; ++rg){ \
    gpart[(rbase + (mt)*16 + rb + rg)*4096 + col] = A1[rg] + A2[rg]*inv; } }
  GSTT(0, c10, c20) GSTT(1, c11, c21) GSTT(2, c12, c22) GSTT(3, c13, c23)
}

// ---- fp32 fallback gates GEMM
#define GWLD(d, off) (*(const float4*)((((d) < DIN) ? (w_ih + (size_t)(d)*4096) \
                       : (w_hh + (size_t)((d)-DIN)*4096)) + (off)))
__global__ __launch_bounds__(256) void k_gates(
    const float* __restrict__ x, const float* __restrict__ w_ih,
    const float* __restrict__ w_hh, float* __restrict__ gpart){
  int tid = threadIdx.x;
  int jt = blockIdx.x, ks = blockIdx.y;
  int cx = tid & 15, ry = tid >> 4;
  int cb = jt*64;
  int wdd = tid >> 4, wseg = tid & 15;
  int xrow = tid >> 3, xseg = tid & 7;

  __shared__ float Wt0[32][64], Wt1[32][64];
  __shared__ float Xt0[32][68], Xt1[32][68];

  float acc[4][4];
  #pragma unroll
  for (int cc=0;cc<4;++cc)
    #pragma unroll
    for (int rr=0;rr<4;++rr) acc[cc][rr]=0.f;

  int d0 = ks*128;
  const float* xp0 = x + (size_t)xrow*D2 + d0 + xseg*4;
  const float* xp1 = x + (size_t)(xrow+32)*D2 + d0 + xseg*4;

#define GLQ(WA,WB,X0,X1, ch) { int d_ = d0 + (ch)*32; \
  WA = GWLD(d_+wdd,    cb+wseg*4); \
  WB = GWLD(d_+16+wdd, cb+wseg*4); \
  X0 = *(const float4*)(xp0 + (ch)*32); \
  X1 = *(const float4*)(xp1 + (ch)*32); }
#define GSQ(Wt,Xt, WA,WB,X0,X1) { \
  *(float4*)&Wt[wdd][wseg*4]    = WA; \
  *(float4*)&Wt[wdd+16][wseg*4] = WB; \
  Xt[xseg*4+0][xrow] = X0.x; Xt[xseg*4+1][xrow] = X0.y; \
  Xt[xseg*4+2][xrow] = X0.z; Xt[xseg*4+3][xrow] = X0.w; \
  Xt[xseg*4+0][xrow+32] = X1.x; Xt[xseg*4+1][xrow+32] = X1.y; \
  Xt[xseg*4+2][xrow+32] = X1.z; Xt[xseg*4+3][xrow+32] = X1.w; }
#define GCQ(Wt,Xt) { _Pragma("unroll 8") for (int dd=0; dd<32; ++dd){ \
    float4 w4 = *(const float4*)&Wt[dd][cx*4]; \
    float4 h4 = *(const float4*)&Xt[dd][ry*4]; \
    FMA16(w4, h4) } }

  float4 wA0,wB0,x00,x10, wA1,wB1,x01,x11;
  GLQ(wA0,wB0,x00,x10, 0)
  GSQ(Wt0,Xt0, wA0,wB0,x00,x10)
  GLQ(wA1,wB1,x01,x11, 1)
  __syncthreads();

  for (int ch=0; ch<4; ch+=2){
    if (ch+2<4) GLQ(wA0,wB0,x00,x10, ch+2)
    GSQ(Wt1,Xt1, wA1,wB1,x01,x11)
    GCQ(Wt0,Xt0)
    __syncthreads();
    if (ch+3<4) GLQ(wA1,wB1,x01,x11, ch+3)
    if (ch+2<4) GSQ(Wt0,Xt0, wA0,wB0,x00,x10)
    GCQ(Wt1,Xt1)
    if (ch+2<4) __syncthreads();
  }
  #pragma unroll
  for (int rr=0;rr<4;++rr){
    float4 o; o.x=acc[0][rr]; o.y=acc[1][rr]; o.z=acc[2][rr]; o.w=acc[3][rr];
    *(float4*)&gpart[((size_t)(ks*R_N + ry*4+rr))*4096 + cb + cx*4] = o;
  }
}

// ---- LSTM: sum nds partial slices + bias, cell update; emit h.
// Split path (hpk != 0): write ONLY packed fragments (h2t/xn fp32 are dead).
__global__ __launch_bounds__(256) void k_lstm(
    const float* __restrict__ gpart, const float* __restrict__ b_lstm,
    float* __restrict__ c, float* __restrict__ xn, float* __restrict__ h2t,
    f16* __restrict__ hpk, f16* __restrict__ xpk, int nds){
  int r = blockIdx.x, tid = threadIdx.x;
  int j = blockIdx.y*256 + tid;
  float gi = b_lstm[j], gf = b_lstm[1024+j], gg = b_lstm[2048+j], go = b_lstm[3072+j];
  for (int ds=0; ds<nds; ++ds){
    size_t base = ((size_t)ds*R_N + r)*4096;
    gi += gpart[base + j];      gf += gpart[base + 1024 + j];
    gg += gpart[base + 2048+j]; go += gpart[base + 3072 + j];
  }
  float cv = c[(size_t)r*H_N + j];
  float c2 = sigmf(gf)*cv + sigmf(gi)*tanhf(gg);
  float h2 = sigmf(go)*tanhf(c2);
  c[(size_t)r*H_N + j] = c2;
  if (hpk){
    f16 hh = (f16)h2;
    int m = r >> 4, lm = r & 15;
    int ks = j >> 5, kq = (j & 31) >> 3, i = j & 7;
    int l = lm + 16*kq;
    size_t base2 = ((size_t)(m*32 + ks)*2)*512 + l*8 + i;
    hpk[base2]       = hh;
    hpk[base2 + 512] = (f16)((h2 - (float)hh)*4096.0f);
    packx(xpk, r, DIN + j, h2);
  } else {
    xn[(size_t)r*D2 + DIN + j] = h2;
    h2t[(size_t)j*R_N + r] = h2;
  }
}

// ---- logits via MFMA fp16-split (K=1024) + fused in-LDS stats.
__global__ __launch_bounds__(256) void k_logits_mfma(
    const f16* __restrict__ wpk, const f16* __restrict__ hpk,
    const float* __restrict__ b_out,
    float* __restrict__ pm, float* __restrict__ pz,
    float* __restrict__ pv, int* __restrict__ pi){
  int tid = threadIdx.x;
  int lane = tid & 63;
  int wv = tid >> 6;
  int T  = blockIdx.x*4 + wv;
  int vb = T*16;

  const f16* wp  = wpk + ((size_t)(T*32))*2*512 + lane*8;
  const f16* hp0 = hpk + ((size_t)(0*32))*2*512 + lane*8;
  const f16* hp1 = hpk + ((size_t)(1*32))*2*512 + lane*8;
  const f16* hp2 = hpk + ((size_t)(2*32))*2*512 + lane*8;
  const f16* hp3 = hpk + ((size_t)(3*32))*2*512 + lane*8;

  DECLFRAGS

  LOADSET(0, 0)
  for (int s=0; s<32; s+=2){
    LOADSET(1, s+1)
    COMPSET(0)
    if (s+2<32) LOADSET(0, s+2)
    COMPSET(1)
  }

  __shared__ float Ls[64][68];

  const float inv = 1.0f/4096.0f;
  int lm = lane & 15;
  int rb = (lane>>4)*4;
  float bias = b_out[vb + lm];
#define STT(mt, A1, A2) { \
  _Pragma("unroll") for (int rg=0; rg<4; ++rg){ \
    Ls[(mt)*16 + rb + rg][wv*16 + lm] = A1[rg] + A2[rg]*inv + bias; } }
  STT(0, c10, c20) STT(1, c11, c21) STT(2, c12, c22) STT(3, c13, c23)
  __syncthreads();

  int cx = tid & 15, ry = tid >> 4;
  int cb = blockIdx.x * 64;
  #pragma unroll
  for (int rr=0;rr<4;++rr){
    int row = ry*4 + rr;
    float v0 = Ls[row][cx*4+0], v1 = Ls[row][cx*4+1];
    float v2 = Ls[row][cx*4+2], v3 = Ls[row][cx*4+3];
    int   c0i = cb + cx*4;
    float tv0=-INFINITY,tv1=-INFINITY,tv2=-INFINITY,tv3=-INFINITY;
    int   ti0=0x7fffffff,ti1=0x7fffffff,ti2=0x7fffffff,ti3=0x7fffffff;
    ins4(v0,c0i+0,tv0,tv1,tv2,tv3,ti0,ti1,ti2,ti3);
    ins4(v1,c0i+1,tv0,tv1,tv2,tv3,ti0,ti1,ti2,ti3);
    ins4(v2,c0i+2,tv0,tv1,tv2,tv3,ti0,ti1,ti2,ti3);
    ins4(v3,c0i+3,tv0,tv1,tv2,tv3,ti0,ti1,ti2,ti3);
    float z = expf(v0-tv0)+expf(v1-tv0)+expf(v2-tv0)+expf(v3-tv0);
    #pragma unroll
    for (int msk=1; msk<16; msk<<=1){
      float om  = __shfl_xor(tv0, msk, 16);
      float oz  = __shfl_xor(z,   msk, 16);
      float ov1 = __shfl_xor(tv1, msk, 16);
      float ov2 = __shfl_xor(tv2, msk, 16);
      float ov3 = __shfl_xor(tv3, msk, 16);
      int   oi0 = __shfl_xor(ti0, msk, 16);
      int   oi1 = __shfl_xor(ti1, msk, 16);
      int   oi2 = __shfl_xor(ti2, msk, 16);
      int   oi3 = __shfl_xor(ti3, msk, 16);
      float M = fmaxf(tv0, om);
      z = z*expf(tv0-M) + oz*expf(om-M);
      ins4(om, oi0, tv0,tv1,tv2,tv3, ti0,ti1,ti2,ti3);
      ins4(ov1,oi1, tv0,tv1,tv2,tv3, ti0,ti1,ti2,ti3);
      ins4(ov2,oi2, tv0,tv1,tv2,tv3, ti0,ti1,ti2,ti3);
      ins4(ov3,oi3, tv0,tv1,tv2,tv3, ti0,ti1,ti2,ti3);
    }
    if (cx == 0){
      size_t base = (size_t)row*NB + blockIdx.x;
      pm[base]=tv0; pz[base]=z;
      pv[base*4+0]=tv0; pv[base*4+1]=tv1; pv[base*4+2]=tv2; pv[base*4+3]=tv3;
      pi[base*4+0]=ti0; pi[base*4+1]=ti1; pi[base*4+2]=ti2; pi[base*4+3]=ti3;
    }
  }
}

// ---- fp32 fallback fused logits+stats
__global__ __launch_bounds__(256) void k_logits_fused(
    const float* __restrict__ h2t, const float* __restrict__ w_out,
    const float* __restrict__ b_out,
    float* __restrict__ pm, float* __restrict__ pz,
    float* __restrict__ pv, int* __restrict__ pi){
  int tid = threadIdx.x;
  int cx  = tid & 15, ry = tid >> 4;
  int cb  = blockIdx.x * 64;
  int sdd = tid >> 4, seg = tid & 15;
  __shared__ float Wt[32][64];
  __shared__ float Ht[32][64];
  float acc[4][4];
  #pragma unroll
  for (int cc=0;cc<4;++cc)
    #pragma unroll
    for (int rr=0;rr<4;++rr) acc[cc][rr]=0.f;
  const float* gW = w_out + (size_t)sdd*V_N + cb + seg*4;
  const float* gH = h2t + sdd*64 + seg*4;
#define FLQ(WA,WB,HA,HB, ch) { \
  const float* gWn = gW + (size_t)(ch)*32*V_N; \
  const float* gHn = gH + (size_t)(ch)*32*64; \
  WA = *(const float4*)gWn; WB = *(const float4*)(gWn + (size_t)16*V_N); \
  HA = *(const float4*)gHn; HB = *(const float4*)(gHn + 16*64); }
#define FSQ(WA,WB,HA,HB) { \
  *(float4*)&Wt[sdd][seg*4]    = WA; \
  *(float4*)&Wt[sdd+16][seg*4] = WB; \
  *(float4*)&Ht[sdd][seg*4]    = HA; \
  *(float4*)&Ht[sdd+16][seg*4] = HB; }
#define FCQ() { _Pragma("unroll 8") for (int dd=0; dd<32; ++dd){ \
    float4 w4 = *(const float4*)&Wt[dd][cx*4]; \
    float4 h4 = *(const float4*)&Ht[dd][ry*4]; \
    FMA16(w4, h4) } }
  float4 wA0,wB0,hA0,hB0, wA1,wB1,hA1,hB1;
  FLQ(wA0,wB0,hA0,hB0, 0)
  FSQ(wA0,wB0,hA0,hB0)
  FLQ(wA1,wB1,hA1,hB1, 1)
  __syncthreads();
  for (int ch=0; ch<32; ch+=2){
    if (ch+2<32) FLQ(wA0,wB0,hA0,hB0, ch+2)
    FCQ()
    __syncthreads();
    FSQ(wA1,wB1,hA1,hB1)
    __syncthreads();
    if (ch+3<32) FLQ(wA1,wB1,hA1,hB1, ch+3)
    FCQ()
    if (ch+2<32){
      __syncthreads();
      FSQ(wA0,wB0,hA0,hB0)
      __syncthreads();
    }
  }
  float4 bias = *(const float4*)&b_out[cb + cx*4];
  #pragma unroll
  for (int rr=0;rr<4;++rr){
    float v0 = acc[0][rr]+bias.x, v1 = acc[1][rr]+bias.y;
    float v2 = acc[2][rr]+bias.z, v3 = acc[3][rr]+bias.w;
    int   c0i = cb + cx*4;
    float tv0=-INFINITY,tv1=-INFINITY,tv2=-INFINITY,tv3=-INFINITY;
    int   ti0=0x7fffffff,ti1=0x7fffffff,ti2=0x7fffffff,ti3=0x7fffffff;
    ins4(v0,c0i+0,tv0,tv1,tv2,tv3,ti0,ti1,ti2,ti3);
    ins4(v1,c0i+1,tv0,tv1,tv2,tv3,ti0,ti1,ti2,ti3);
    ins4(v2,c0i+2,tv0,tv1,tv2,tv3,ti0,ti1,ti2,ti3);
    ins4(v3,c0i+3,tv0,tv1,tv2,tv3,ti0,ti1,ti2,ti3);
    float z = expf(v0-tv0)+expf(v1-tv0)+expf(v2-tv0)+expf(v3-tv0);
    #pragma unroll
    for (int msk=1; msk<16; msk<<=1){
      float om  = __shfl_xor(tv0, msk, 16);
      float oz  = __shfl_xor(z,   msk, 16);
      float ov1 = __shfl_xor(tv1, msk, 16);
      float ov2 = __shfl_xor(tv2, msk, 16);
      float ov3 = __shfl_xor(tv3, msk, 16);
      int   oi0 = __shfl_xor(ti0, msk, 16);
      int   oi1 = __shfl_xor(ti1, msk, 16);
      int   oi2 = __shfl_xor(ti2, msk, 16);
      int   oi3 = __shfl_xor(ti3, msk, 16);
      float M = fmaxf(tv0, om);
      z = z*expf(tv0-M) + oz*expf(om-M);
      ins4(om, oi0, tv0,tv1,tv2,tv3, ti0,ti1,ti2,ti3);
      ins4(ov1,oi1, tv0,tv1,tv2,tv3, ti0,ti1,ti2,ti3);
      ins4(ov2,oi2, tv0,tv1,tv2,tv3, ti0,ti1,ti2,ti3);
      ins4(ov3,oi3, tv0,tv1,tv2,tv3, ti0,ti1,ti2,ti3);
    }
    if (cx == 0){
      int row = ry*4 + rr;
      size_t base = (size_t)row*NB + blockIdx.x;
      pm[base]=tv0; pz[base]=z;
      pv[base*4+0]=tv0; pv[base*4+1]=tv1; pv[base*4+2]=tv2; pv[base*4+3]=tv3;
      pi[base*4+0]=ti0; pi[base*4+1]=ti1; pi[base*4+2]=ti2; pi[base*4+3]=ti3;
    }
  }
}

// ---- final: per-beam wave reduce + joint top-4 + next-x assembly (+pack)
__global__ __launch_bounds__(256) void k_final(
    const float* __restrict__ pm, const float* __restrict__ pz,
    const float* __restrict__ pv, const int* __restrict__ pi,
    float* __restrict__ scores, int* __restrict__ out, int t,
    float* __restrict__ xn, f16* __restrict__ xpk,
    const float* __restrict__ enc_inputs, const float* __restrict__ enc_outputs,
    const float* __restrict__ embed){
  int b = blockIdx.x, tid = threadIdx.x;
  int kk = tid >> 6, lane = tid & 63;
  __shared__ float fM[KBEAM], fZ[KBEAM], fV[16];
  __shared__ int   fI[16], sw[KBEAM];
  int nk = (t==0) ? 1 : KBEAM;
  if (kk < nk){
    size_t rb = (size_t)(kk*B_N + b)*NB;
    float m=-INFINITY, z=0.f;
    float av0=-INFINITY,av1=-INFINITY,av2=-INFINITY,av3=-INFINITY;
    int   ai0=0x7fffffff,ai1=0x7fffffff,ai2=0x7fffffff,ai3=0x7fffffff;
    for (int p0=lane; p0<NB; p0+=64){
      size_t p = rb + p0;
      float mf = pm[p];
      float M = fmaxf(m, mf);
      z = z*expf(m-M) + pz[p]*expf(mf-M);
      m = M;
      #pragma unroll
      for (int q=0;q<4;++q)
        ins4(pv[p*4+q], pi[p*4+q], av0,av1,av2,av3, ai0,ai1,ai2,ai3);
    }
    #pragma unroll
    for (int msk=1; msk<64; msk<<=1){
      float om  = __shfl_xor(m,   msk);
      float oz  = __shfl_xor(z,   msk);
      float ov0 = __shfl_xor(av0, msk);
      float ov1 = __shfl_xor(av1, msk);
      float ov2 = __shfl_xor(av2, msk);
      float ov3 = __shfl_xor(av3, msk);
      int   oi0 = __shfl_xor(ai0, msk);
      int   oi1 = __shfl_xor(ai1, msk);
      int   oi2 = __shfl_xor(ai2, msk);
      int   oi3 = __shfl_xor(ai3, msk);
      float M = fmaxf(m, om);
      z = z*expf(m-M) + oz*expf(om-M);
      m = M;
      ins4(ov0,oi0, av0,av1,av2,av3, ai0,ai1,ai2,ai3);
      ins4(ov1,oi1, av0,av1,av2,av3, ai0,ai1,ai2,ai3);
      ins4(ov2,oi2, av0,av1,av2,av3, ai0,ai1,ai2,ai3);
      ins4(ov3,oi3, av0,av1,av2,av3, ai0,ai1,ai2,ai3);
    }
    if (lane == 0){
      fM[kk]=m; fZ[kk]=z;
      fV[kk*4+0]=av0; fV[kk*4+1]=av1; fV[kk*4+2]=av2; fV[kk*4+3]=av3;
      fI[kk*4+0]=ai0; fI[kk*4+1]=ai1; fI[kk*4+2]=ai2; fI[kk*4+3]=ai3;
    }
  }
  __syncthreads();
  if (tid==0){
    if (t==0){
      #pragma unroll
      for (int j=0;j<4;++j){
        float p = expf(fV[j]-fM[0])/fZ[0];
        scores[b*4+j] = p;
        out[j*(B_N*S_LEN) + b*S_LEN] = fI[j];
        sw[j] = fI[j];
      }
    } else {
      float cv[16]; int cj[16];
      for (int k=0;k<4;++k){
        float s = scores[b*4+k];
        #pragma unroll
        for (int j=0;j<4;++j){
          cv[k*4+j] = expf(fV[k*4+j]-fM[k])/fZ[k]*s;
          cj[k*4+j] = k*V_N + fI[k*4+j];
        }
      }
      bool used[16];
      for (int i=0;i<16;++i) used[i]=false;
      for (int rank=0;rank<4;++rank){
        int best=-1;
        for (int i=0;i<16;++i){
          if (used[i]) continue;
          if (best<0 || cv[i]>cv[best] || (cv[i]==cv[best] && cj[i]<cj[best])) best=i;
        }
        used[best]=true;
        out[rank*(B_N*S_LEN) + b*S_LEN + t] = cj[best];
        sw[rank] = cj[best] % V_N;
      }
    }
  }
  __syncthreads();
  if (t < S_LEN-1){
    const float* ein = enc_inputs  + (size_t)(t+1)*B_N*E_N + (size_t)b*E_N;
    const float* eo  = enc_outputs + (size_t)(t+1)*B_N*H_N + (size_t)b*H_N;
    #pragma unroll
    for (int j=0;j<KBEAM;++j){
      int r = j*B_N + b;
      const float* em = embed + (size_t)sw[j]*E_N;
      float v0 = em[tid], v1 = ein[tid];
      if (xpk){
        packx(xpk, r, tid, v0); packx(xpk, r, E_N + tid, v1);
        #pragma unroll
        for (int q=0;q<4;++q) packx(xpk, r, 2*E_N + q*256 + tid, eo[q*256 + tid]);
      } else {
        float* xr = xn + (size_t)r*D2;
        xr[tid]       = v0;
        xr[E_N + tid] = v1;
        #pragma unroll
        for (int q=0;q<4;++q) xr[2*E_N + q*256 + tid] = eo[q*256 + tid];
      }
    }
  }
}

extern "C" void kernel_launch(void* const* d_in, const int* in_sizes, int n_in,
                              void* d_out, int out_size, void* d_ws, size_t ws_size,
                              hipStream_t stream) {
  (void)in_sizes; (void)n_in; (void)out_size;
  const float* enc_h_n     = (const float*)d_in[0];
  const float* enc_c_n     = (const float*)d_in[1];
  const float* enc_outputs = (const float*)d_in[2];
  const float* enc_inputs  = (const float*)d_in[3];
  const float* embed       = (const float*)d_in[4];
  const float* w_ih        = (const float*)d_in[5];
  const float* w_hh        = (const float*)d_in[6];
  const float* b_lstm      = (const float*)d_in[7];
  const float* w_out       = (const float*)d_in[8];
  const float* b_out       = (const float*)d_in[9];
  int* out = (int*)d_out;

  float* ws = (float*)d_ws;
  const size_t FRONTF = (size_t)R_N*D2*2 + (size_t)R_N*H_N + (size_t)H_N*R_N; // 458752
  const size_t HSPLF  = (size_t)R_N*H_N;         // hpk pair
  const size_t XPKF   = (size_t)R_N*D2;          // xpk pair
  const size_t GPARTF = (size_t)NDS*R_N*4096;    // fallback max
  const size_t STATF  = (size_t)R_N*NB*10;
  const size_t WSPLF  = (size_t)V_N*H_N;         // wpk pair (128 MB)
  const size_t WGPKF  = (size_t)D2*4096;         // wgpk pair (42 MB)
  size_t need_split = (FRONTF + HSPLF + XPKF + GPARTF + STATF + 64 + WSPLF + WGPKF)*sizeof(float);
  bool use_split = (ws_size >= need_split);

  float* xA     = ws;
  float* xB     = xA + (size_t)R_N*D2;
  float* cbuf   = xB + (size_t)R_N*D2;
  float* h2t    = cbuf + (size_t)R_N*H_N;
  f16*   hpk    = (f16*)(h2t + (size_t)H_N*R_N);
  f16*   xpk    = (f16*)(h2t + (size_t)H_N*R_N + HSPLF);
  float* big    = h2t + (size_t)H_N*R_N + HSPLF + XPKF;
  float* gpart  = big;
  float* pm     = big + GPARTF;
  float* pz     = pm + (size_t)R_N*NB;
  float* pv     = pz + (size_t)R_N*NB;
  int*   pi     = (int*)(pv + (size_t)R_N*NB*4);
  float* scoresb= (float*)(pi + (size_t)R_N*NB*4);
  f16*   wpk    = (f16*)(scoresb + 64);
  f16*   wgpk   = (f16*)((float*)(scoresb + 64) + WSPLF);

  f16* hpk_arg = use_split ? hpk : (f16*)0;
  f16* xpk_arg = use_split ? xpk : (f16*)0;

  if (use_split){
    k_convw<<<dim3(V_N/64, H_N/64), 256, 0, stream>>>(w_out, wpk);
    k_convg<<<dim3(4096/64, D2/64), 256, 0, stream>>>(w_ih, w_hh, wgpk);
  }
  k_init<<<R_N, 256, 0, stream>>>(enc_h_n, enc_c_n, enc_outputs, enc_inputs,
                                  embed, xA, cbuf, xpk_arg);

  for (int t=0; t<S_LEN; ++t){
    float* xc = (t & 1) ? xB : xA;
    float* xn = (t & 1) ? xA : xB;
    if (use_split){
      k_gates_mfma<<<dim3(64, GKS), 256, 0, stream>>>(wgpk, xpk, gpart);
      k_lstm<<<dim3(R_N, 4), 256, 0, stream>>>(gpart, b_lstm, cbuf, xn, h2t,
                                               hpk_arg, xpk_arg, GKS);
      k_logits_mfma<<<NB, 256, 0, stream>>>(wpk, hpk, b_out, pm, pz, pv, pi);
    } else {
      k_gates <<<dim3(64, NDS), 256, 0, stream>>>(xc, w_ih, w_hh, gpart);
      k_lstm<<<dim3(R_N, 4), 256, 0, stream>>>(gpart, b_lstm, cbuf, xn, h2t,
                                               (f16*)0, (f16*)0, NDS);
      k_logits_fused<<<NB, 256, 0, stream>>>(h2t, w_out, b_out, pm, pz, pv, pi);
    }
    k_final <<<B_N, 256, 0, stream>>>(pm, pz, pv, pi, scoresb, out, t, xn, xpk_arg,
                                      enc_inputs, enc_outputs, embed);
  }
}